// Round 1
// 914.158 us; speedup vs baseline: 1.0089x; 1.0089x over previous
//
#include <hip/hip_runtime.h>
#include <math.h>

// Problem constants (Compress_30047591202836)
constexpr int S_   = 2048;
constexpr int H_   = 2048;
constexpr int NH_  = 32;
constexpr int NKV_ = 8;
constexpr int HD_  = 64;
constexpr int GROUPS_ = NH_ / NKV_;     // 4
constexpr int KV_  = NKV_ * HD_;        // 512
constexpr int KV2_ = 2 * KV_;           // 1024 (k|v fused)
constexpr int COMP_ = 1024;             // S * 0.5
constexpr int FF_  = 5632;
constexpr int GU2_ = 2 * FF_;           // 11264 (gate|up fused)
constexpr int TOT_ = S_ + COMP_;        // 3072
constexpr float EPS_ = 1e-6f;
constexpr int SK_ = 4;                  // split-K factor (GEMMs)
constexpr int SP_ = 2;                  // KV-split factor (attention)
constexpr float LOG2E_ = 1.44269504088896340736f;

typedef __attribute__((ext_vector_type(4))) float f32x4;
typedef __attribute__((ext_vector_type(8))) short bf16x8;
typedef __attribute__((ext_vector_type(8))) ushort u16x8;

__device__ __forceinline__ ushort f2bf(float x) {
    union { float f; unsigned u; } v; v.f = x;
    unsigned r = v.u + 0x7fffu + ((v.u >> 16) & 1u);   // RNE
    return (ushort)(r >> 16);
}
__device__ __forceinline__ float bf2f(ushort x) {
    union { unsigned u; float f; } v; v.u = ((unsigned)x) << 16;
    return v.f;
}

// ---------------------------------------------------------------------------
// fp32 -> bf16 convert, float4/ushort4 grid-stride. n4 = n/4.
// ---------------------------------------------------------------------------
__global__ __launch_bounds__(256) void f2b_k(
    const float* __restrict__ x, ushort* __restrict__ y, int n4)
{
    int i = blockIdx.x * 256 + threadIdx.x;
    const int stride = gridDim.x * 256;
    for (; i < n4; i += stride) {
        float4 v = ((const float4*)x)[i];
        ushort4 r = {f2bf(v.x), f2bf(v.y), f2bf(v.z), f2bf(v.w)};
        ((ushort4*)y)[i] = r;
    }
}

// ---------------------------------------------------------------------------
// bf16 64x64 tiled transpose: out[(c0+j)*R + r] = in[(r0+r)*ldi + c0+j].
// ---------------------------------------------------------------------------
__global__ __launch_bounds__(256) void tpose64(
    const ushort* __restrict__ in, ushort* __restrict__ out,
    int R, int C, int ldi)
{
    __shared__ ushort T[64][72];
    const int r0 = blockIdx.x * 64, c0 = blockIdx.y * 64;
    const int row = threadIdx.x >> 2, seg = threadIdx.x & 3;

    const ushort* g = &in[(size_t)(r0 + row) * ldi + c0 + seg * 16];
    *(u16x8*)&T[row][seg * 16]     = *(const u16x8*)g;
    *(u16x8*)&T[row][seg * 16 + 8] = *(const u16x8*)(g + 8);
    __syncthreads();

    ushort tmp[16];
#pragma unroll
    for (int j = 0; j < 16; j++) tmp[j] = T[seg * 16 + j][row];
    ushort* go = &out[(size_t)(c0 + row) * R + r0 + seg * 16];
    *(u16x8*)go       = *(const u16x8*)&tmp[0];
    *(u16x8*)(go + 8) = *(const u16x8*)&tmp[8];
}

// ---------------------------------------------------------------------------
// bf16 MFMA GEMM (non-split): C = oscale*(A@B^T)+bias+addp -> outf/outb.
// 128x128 tile, BK=32, 4 waves, 4x4 mfma_f32_16x16x32_bf16 per wave.
// (kept as fallback; no longer used for gate|up)
// ---------------------------------------------------------------------------
__global__ __launch_bounds__(256) void mfma_gemm(
    const ushort* __restrict__ A, const ushort* __restrict__ B,
    const float* __restrict__ addp, const float* __restrict__ bias,
    float oscale, float* __restrict__ outf, ushort* __restrict__ outb,
    int M, int N, int K)
{
    __shared__ ushort Alds[128 * 32];
    __shared__ ushort Blds[128 * 32];

    const int tid  = threadIdx.x;
    const int w    = tid >> 6;
    const int lane = tid & 63;
    const int bm = blockIdx.y, bn = blockIdx.x;
    const int wr = w >> 1, wc = w & 1;
    const int fr = lane & 15;
    const int fq = lane >> 4;
    const int srow = lane >> 2;
    const int skof = (lane & 3) * 8;

    f32x4 acc[4][4];
#pragma unroll
    for (int i = 0; i < 4; i++)
#pragma unroll
        for (int j = 0; j < 4; j++)
            acc[i][j] = (f32x4){0.f, 0.f, 0.f, 0.f};

    for (int k0 = 0; k0 < K; k0 += 32) {
        __syncthreads();
#pragma unroll
        for (int i = 0; i < 2; i++) {
            const int slot = w * 2 + i;
            const ushort* ga = &A[(size_t)(bm * 128 + slot * 16 + srow) * K + k0 + skof];
            __builtin_amdgcn_global_load_lds(
                (const __attribute__((address_space(1))) void*)ga,
                (__attribute__((address_space(3))) void*)&Alds[slot * 512], 16, 0, 0);
            const ushort* gb = &B[(size_t)(bn * 128 + slot * 16 + srow) * K + k0 + skof];
            __builtin_amdgcn_global_load_lds(
                (const __attribute__((address_space(1))) void*)gb,
                (__attribute__((address_space(3))) void*)&Blds[slot * 512], 16, 0, 0);
        }
        __syncthreads();

        bf16x8 a[4], b[4];
#pragma unroll
        for (int mt = 0; mt < 4; mt++)
            a[mt] = *(const bf16x8*)&Alds[(wr * 64 + mt * 16 + fr) * 32 + fq * 8];
#pragma unroll
        for (int nt = 0; nt < 4; nt++)
            b[nt] = *(const bf16x8*)&Blds[(wc * 64 + nt * 16 + fr) * 32 + fq * 8];

#pragma unroll
        for (int mt = 0; mt < 4; mt++)
#pragma unroll
            for (int nt = 0; nt < 4; nt++)
                acc[mt][nt] = __builtin_amdgcn_mfma_f32_16x16x32_bf16(
                    a[mt], b[nt], acc[mt][nt], 0, 0, 0);
    }

#pragma unroll
    for (int mt = 0; mt < 4; mt++) {
#pragma unroll
        for (int nt = 0; nt < 4; nt++) {
#pragma unroll
            for (int r = 0; r < 4; r++) {
                const int row = bm * 128 + wr * 64 + mt * 16 + fq * 4 + r;
                const int col = bn * 128 + wc * 64 + nt * 16 + fr;
                float v = acc[mt][nt][r] * oscale;
                if (bias) v += bias[row];
                if (addp) v += addp[(size_t)row * N + col];
                if (outf) outf[(size_t)row * N + col] = v;
                if (outb) outb[(size_t)row * N + col] = f2bf(v);
            }
        }
    }
}

// ---------------------------------------------------------------------------
// 256x256-tile 8-phase counted-vmcnt bf16 GEMM (guide §5 template, plain HIP).
//   C(bf16) = A @ B^T, A:(M,K) B:(N,K) bf16, M%256==0, N%256==0, K%128==0.
// 512 threads = 8 waves (2M x 4N), per-wave C 128x64, BK=64, acc[8][4].
// LDS 128 KiB: [A0|B0|A1|B1] each 256x64 bf16, XOR-swizzled
//   phys_slot16B = logical_slot16B ^ (row & 7)     (T2; conflict-free ds_read)
// staged by pre-swizzling the per-lane GLOBAL source (rule #21: gload_lds dest
// must stay linear). 8 phases / 2 K-tiles per iter; one half-tile (2 x
// global_load_lds_dwordx4) staged per phase; vmcnt(6) waits only at phases
// 4 and 8 (3 half-tiles stay in flight, T4). s_setprio around MFMA (T5).
// Stage slot safety: each slot writes a region whose last reader finished
// before the preceding barrier; each read's data is covered by the prior
// vmcnt(6)+barrier. Main loop iters 0..NT/2-2; peeled last pair drains
// vmcnt(0) at its phase 4.
// ---------------------------------------------------------------------------
#define BARS do { __builtin_amdgcn_s_barrier(); __builtin_amdgcn_sched_barrier(0); } while (0)
#define VMW(n) asm volatile("s_waitcnt vmcnt(" #n ")" ::: "memory")
#define STG(gp, lp) __builtin_amdgcn_global_load_lds( \
    (const __attribute__((address_space(1))) void*)(gp), \
    (__attribute__((address_space(3))) void*)(lp), 16, 0, 0)
#define STA(bufA, R0, kt) STG(Ag + (size_t)(R0) * K + (kt) * 64, &(bufA)[((R0) + w * 8) * 64])
#define STB(bufB, R0, kt) STG(Bg + (size_t)(R0) * K + (kt) * 64, &(bufB)[((R0) + w * 8) * 64])

__device__ __forceinline__ void ldaq(bf16x8 (&aa)[2][2], const ushort* bufA,
                                     int m0, int aoff, int s0, int s1)
{
#pragma unroll
    for (int m = 0; m < 2; m++) {
        aa[m][0] = *(const bf16x8*)&bufA[aoff + (m0 + m) * 1024 + s0];
        aa[m][1] = *(const bf16x8*)&bufA[aoff + (m0 + m) * 1024 + s1];
    }
}
__device__ __forceinline__ void ldbq(bf16x8 (&bb)[4][2], const ushort* bufB,
                                     int boff, int s0, int s1)
{
#pragma unroll
    for (int nt = 0; nt < 4; nt++) {
        bb[nt][0] = *(const bf16x8*)&bufB[boff + nt * 1024 + s0];
        bb[nt][1] = *(const bf16x8*)&bufB[boff + nt * 1024 + s1];
    }
}
template <int M0>
__device__ __forceinline__ void mfmaq(f32x4 (&acc)[8][4], bf16x8 (&aa)[2][2],
                                      bf16x8 (&bb)[4][2])
{
    __builtin_amdgcn_s_setprio(1);
#pragma unroll
    for (int m = 0; m < 2; m++)
#pragma unroll
        for (int nt = 0; nt < 4; nt++) {
            acc[M0 + m][nt] = __builtin_amdgcn_mfma_f32_16x16x32_bf16(
                aa[m][0], bb[nt][0], acc[M0 + m][nt], 0, 0, 0);
            acc[M0 + m][nt] = __builtin_amdgcn_mfma_f32_16x16x32_bf16(
                aa[m][1], bb[nt][1], acc[M0 + m][nt], 0, 0, 0);
        }
    __builtin_amdgcn_s_setprio(0);
}

__global__ __launch_bounds__(512, 2) void gemm8ph(
    const ushort* __restrict__ A, const ushort* __restrict__ B,
    ushort* __restrict__ C, int N, int K)
{
    alignas(16) __shared__ ushort lds[4][16384];   // A0,B0,A1,B1 (32 KiB each)
    ushort* const lA0 = lds[0];
    ushort* const lB0 = lds[1];
    ushort* const lA1 = lds[2];
    ushort* const lB1 = lds[3];

    const int tid = threadIdx.x;
    const int w = tid >> 6, lane = tid & 63;
    const int wr = w >> 2, wc = w & 3;
    const int fr = lane & 15, fq = lane >> 4;
    const int xk = fr & 7;

    // T1: XCD-aware block swizzle (bijective; nwg % 8 == 0 for gate|up grid)
    const int nwg = gridDim.x;
    const int nbn = N >> 8;
    int id = (int)blockIdx.x;
    if (!(nwg & 7)) id = (id & 7) * (nwg >> 3) + (id >> 3);
    const int bm = id / nbn, bn = id - bm * nbn;

    // staging: lane -> (row = w*8 + lane>>3, phys slot = lane&7); the global
    // source column is pre-swizzled so linear LDS dest realizes the XOR layout
    const int srow = lane >> 3;
    const int scol = ((lane & 7) ^ srow) << 3;     // elements
    const ushort* Ag = A + (size_t)(bm * 256 + w * 8 + srow) * K + scol;
    const ushort* Bg = B + (size_t)(bn * 256 + w * 8 + srow) * K + scol;

    // ds_read bases: logical (row, slot) -> phys byte row*128 + ((slot^row&7)<<4)
    const int aoff = (wr * 128 + fr) * 64;
    const int boff = (wc * 64 + fr) * 64;
    const int s0 = ((0 + fq) ^ xk) << 3;           // kk=0 slot, elements
    const int s1 = ((4 + fq) ^ xk) << 3;           // kk=1 slot

    f32x4 acc[8][4];
#pragma unroll
    for (int i = 0; i < 8; i++)
#pragma unroll
        for (int j = 0; j < 4; j++) acc[i][j] = (f32x4){0.f, 0.f, 0.f, 0.f};

    bf16x8 aa[2][2], bb[4][2];

    // ---- prologue: tile0 complete (8 halves... 4 half-tiles) + tile1 minus A-h2
    STB(lB0, 0, 0);   STB(lB0, 64, 0);
    STA(lA0, 0, 0);   STA(lA0, 128, 0);
    STB(lB0, 128, 0); STB(lB0, 192, 0);
    STA(lA0, 64, 0);  STA(lA0, 192, 0);
    STB(lB1, 0, 1);   STB(lB1, 64, 1);
    STA(lA1, 0, 1);   STA(lA1, 128, 1);
    STB(lB1, 128, 1); STB(lB1, 192, 1);
    VMW(6);            // tile 0 landed; tile 1's 3 half-tiles may be in flight
    BARS;

    const int NITER = K >> 7;          // pairs of BK=64 tiles
    for (int i = 0; i < NITER - 1; i++) {
        const int t1 = 2 * i + 1, t2 = 2 * i + 2, t3 = 2 * i + 3;
        // P1: tile 2i quadrant 0 (buf0); stage A1 h2 for tile 2i+1
        ldbq(bb, lB0, boff, s0, s1);
        ldaq(aa, lA0, 0, aoff, s0, s1);
        STA(lA1, 64, t1); STA(lA1, 192, t1);
        BARS; mfmaq<0>(acc, aa, bb); BARS;
        // P2: quadrant 1; stage B0 h1 (tile 2i+2)
        ldaq(aa, lA0, 2, aoff, s0, s1);
        STB(lB0, 0, t2); STB(lB0, 64, t2);
        BARS; mfmaq<2>(acc, aa, bb); BARS;
        // P3: quadrant 2; stage A0 h1 (tile 2i+2)
        ldaq(aa, lA0, 4, aoff, s0, s1);
        STA(lA0, 0, t2); STA(lA0, 128, t2);
        BARS; mfmaq<4>(acc, aa, bb); BARS;
        // P4: quadrant 3; stage B0 h2; counted wait (3 half-tiles remain in flight)
        ldaq(aa, lA0, 6, aoff, s0, s1);
        STB(lB0, 128, t2); STB(lB0, 192, t2);
        BARS; mfmaq<6>(acc, aa, bb); VMW(6); BARS;
        // P5: tile 2i+1 quadrant 0 (buf1); stage A0 h2 (tile 2i+2)
        ldbq(bb, lB1, boff, s0, s1);
        ldaq(aa, lA1, 0, aoff, s0, s1);
        STA(lA0, 64, t2); STA(lA0, 192, t2);
        BARS; mfmaq<0>(acc, aa, bb); BARS;
        // P6: quadrant 1; stage B1 h1 (tile 2i+3)
        ldaq(aa, lA1, 2, aoff, s0, s1);
        STB(lB1, 0, t3); STB(lB1, 64, t3);
        BARS; mfmaq<2>(acc, aa, bb); BARS;
        // P7: quadrant 2; stage A1 h1 (tile 2i+3)
        ldaq(aa, lA1, 4, aoff, s0, s1);
        STA(lA1, 0, t3); STA(lA1, 128, t3);
        BARS; mfmaq<4>(acc, aa, bb); BARS;
        // P8: quadrant 3; stage B1 h2; counted wait
        ldaq(aa, lA1, 6, aoff, s0, s1);
        STB(lB1, 128, t3); STB(lB1, 192, t3);
        BARS; mfmaq<6>(acc, aa, bb); VMW(6); BARS;
    }
    // ---- peeled last pair (tiles 2*NITER-2, 2*NITER-1): no future prefetch
    {
        const int t1 = 2 * NITER - 1;
        ldbq(bb, lB0, boff, s0, s1);
        ldaq(aa, lA0, 0, aoff, s0, s1);
        STA(lA1, 64, t1); STA(lA1, 192, t1);
        BARS; mfmaq<0>(acc, aa, bb); BARS;
        ldaq(aa, lA0, 2, aoff, s0, s1);
        BARS; mfmaq<2>(acc, aa, bb); BARS;
        ldaq(aa, lA0, 4, aoff, s0, s1);
        BARS; mfmaq<4>(acc, aa, bb); BARS;
        ldaq(aa, lA0, 6, aoff, s0, s1);
        BARS; mfmaq<6>(acc, aa, bb); VMW(0); BARS;   // drain: all of tile t1 landed
        ldbq(bb, lB1, boff, s0, s1);
        ldaq(aa, lA1, 0, aoff, s0, s1);
        BARS; mfmaq<0>(acc, aa, bb); BARS;
        ldaq(aa, lA1, 2, aoff, s0, s1);
        BARS; mfmaq<2>(acc, aa, bb); BARS;
        ldaq(aa, lA1, 4, aoff, s0, s1);
        BARS; mfmaq<4>(acc, aa, bb); BARS;
        ldaq(aa, lA1, 6, aoff, s0, s1);
        mfmaq<6>(acc, aa, bb);
    }

    // ---- epilogue: bf16 C write
    ushort* Cb = C + (size_t)(bm * 256 + wr * 128 + fq * 4) * N
                   + bn * 256 + wc * 64 + fr;
#pragma unroll
    for (int mt = 0; mt < 8; mt++)
#pragma unroll
        for (int nt = 0; nt < 4; nt++)
#pragma unroll
            for (int r = 0; r < 4; r++)
                Cb[(size_t)(mt * 16 + r) * N + nt * 16] = f2bf(acc[mt][nt][r]);
}

// ---------------------------------------------------------------------------
// Split-K MFMA GEMM: grid.z = SK slices of K. Raw fp32 partials to part.
// ---------------------------------------------------------------------------
__global__ __launch_bounds__(256) void mfma_gemm_sk(
    const ushort* __restrict__ A, const ushort* __restrict__ B,
    float* __restrict__ part, int M, int N, int K, int Kc)
{
    __shared__ ushort Alds[128 * 32];
    __shared__ ushort Blds[128 * 32];

    const int tid  = threadIdx.x;
    const int w    = tid >> 6;
    const int lane = tid & 63;
    const int bm = blockIdx.y, bn = blockIdx.x, z = blockIdx.z;
    const int wr = w >> 1, wc = w & 1;
    const int fr = lane & 15;
    const int fq = lane >> 4;
    const int srow = lane >> 2;
    const int skof = (lane & 3) * 8;

    f32x4 acc[4][4];
#pragma unroll
    for (int i = 0; i < 4; i++)
#pragma unroll
        for (int j = 0; j < 4; j++)
            acc[i][j] = (f32x4){0.f, 0.f, 0.f, 0.f};

    const int kbeg = z * Kc;
    for (int k0 = kbeg; k0 < kbeg + Kc; k0 += 32) {
        __syncthreads();
#pragma unroll
        for (int i = 0; i < 2; i++) {
            const int slot = w * 2 + i;
            const ushort* ga = &A[(size_t)(bm * 128 + slot * 16 + srow) * K + k0 + skof];
            __builtin_amdgcn_global_load_lds(
                (const __attribute__((address_space(1))) void*)ga,
                (__attribute__((address_space(3))) void*)&Alds[slot * 512], 16, 0, 0);
            const ushort* gb = &B[(size_t)(bn * 128 + slot * 16 + srow) * K + k0 + skof];
            __builtin_amdgcn_global_load_lds(
                (const __attribute__((address_space(1))) void*)gb,
                (__attribute__((address_space(3))) void*)&Blds[slot * 512], 16, 0, 0);
        }
        __syncthreads();

        bf16x8 a[4], b[4];
#pragma unroll
        for (int mt = 0; mt < 4; mt++)
            a[mt] = *(const bf16x8*)&Alds[(wr * 64 + mt * 16 + fr) * 32 + fq * 8];
#pragma unroll
        for (int nt = 0; nt < 4; nt++)
            b[nt] = *(const bf16x8*)&Blds[(wc * 64 + nt * 16 + fr) * 32 + fq * 8];

#pragma unroll
        for (int mt = 0; mt < 4; mt++)
#pragma unroll
            for (int nt = 0; nt < 4; nt++)
                acc[mt][nt] = __builtin_amdgcn_mfma_f32_16x16x32_bf16(
                    a[mt], b[nt], acc[mt][nt], 0, 0, 0);
    }

    float* pz = part + (size_t)z * M * N;
#pragma unroll
    for (int mt = 0; mt < 4; mt++)
#pragma unroll
        for (int nt = 0; nt < 4; nt++)
#pragma unroll
            for (int r = 0; r < 4; r++) {
                const int row = bm * 128 + wr * 64 + mt * 16 + fq * 4 + r;
                const int col = bn * 128 + wc * 64 + nt * 16 + fr;
                pz[(size_t)row * N + col] = acc[mt][nt][r];
            }
}

// ---------------------------------------------------------------------------
// Split-K reduce + epilogue.
// ---------------------------------------------------------------------------
__global__ __launch_bounds__(256) void sk_reduce(
    const float* __restrict__ part, int mn4, int n4,
    const float* __restrict__ bias, const float* __restrict__ addp,
    float oscale, float* __restrict__ outf, ushort* __restrict__ outb)
{
    const size_t mn = (size_t)mn4 * 4;
    int i = blockIdx.x * 256 + threadIdx.x;
    const int stride = gridDim.x * 256;
    for (; i < mn4; i += stride) {
        float4 v = ((const float4*)part)[i];
#pragma unroll
        for (int z = 1; z < SK_; z++) {
            const float4 pz = ((const float4*)(part + z * mn))[i];
            v.x += pz.x; v.y += pz.y; v.z += pz.z; v.w += pz.w;
        }
        v.x *= oscale; v.y *= oscale; v.z *= oscale; v.w *= oscale;
        if (bias) {
            const float bb = bias[i / n4];
            v.x += bb; v.y += bb; v.z += bb; v.w += bb;
        }
        if (addp) {
            const float4 ad = ((const float4*)addp)[i];
            v.x += ad.x; v.y += ad.y; v.z += ad.z; v.w += ad.w;
        }
        if (outf) ((float4*)outf)[i] = v;
        if (outb) {
            ushort4 r = {f2bf(v.x), f2bf(v.y), f2bf(v.z), f2bf(v.w)};
            ((ushort4*)outb)[i] = r;
        }
    }
}

// ---------------------------------------------------------------------------
// MFMA flash attention, KV-split, S^T formulation.
//   q : (COMP_, H_) bf16, PRE-SCALED by log2(e)/sqrt(HD)  (exp2 domain)
//   k : fused kv buffer rows, row-stride ldk (k half)
//   vt: (KV_, TOT_) bf16 transposed V
// S^T = K·Q^T per key-tile: C-layout gives lane (fr,fq) row qrow=fr, keys
// nt*16+fq*4+r — softmax is in-lane + 2 shuffles, and P stores are 4x b64
// (contiguous in key) instead of 16x b16. Q fragments load straight from
// global (B-operand layout), no Q LDS array. LDS = 3 x 9 KB = 27 KB.
// Emits unnormalized fp32 O-partials (attp[z]) + per-row (m,l) pairs (ml).
// ---------------------------------------------------------------------------
__global__ __launch_bounds__(256) void attn_mfma(
    const ushort* __restrict__ q, const ushort* __restrict__ k, int ldk,
    const ushort* __restrict__ vt, float* __restrict__ attp,
    float* __restrict__ ml)
{
    constexpr int LDT = 72;
    constexpr int KSPAN = TOT_ / SP_;   // 1536 keys per split
    __shared__ ushort Ks[64 * LDT];
    __shared__ ushort Vs[64 * LDT];
    __shared__ ushort Ps[64 * LDT];

    const int qt = blockIdx.x, h = blockIdx.y, z = blockIdx.z;
    const int kvh = h / GROUPS_;
    const int tid = threadIdx.x;
    const int w = tid >> 6, lane = tid & 63;
    const int fr = lane & 15, fq = lane >> 4;
    const int q0 = qt * 64;

    // Q B-fragments straight from global: B[n=fr][k=fq*8+j] (+32 half)
    const ushort* qrow = &q[(size_t)(q0 + w * 16 + fr) * H_ + h * HD_];
    const bf16x8 bq0 = *(const bf16x8*)(qrow + fq * 8);
    const bf16x8 bq1 = *(const bf16x8*)(qrow + 32 + fq * 8);

    float m = -1e30f, l = 0.f;          // per-lane row state (row = fr)
    f32x4 acc[4];
#pragma unroll
    for (int nt = 0; nt < 4; nt++) acc[nt] = (f32x4){0.f, 0.f, 0.f, 0.f};

    const int t_beg = z * KSPAN;
    for (int t0 = t_beg; t0 < t_beg + KSPAN; t0 += 64) {
        __syncthreads();   // all waves done reading prev Ks/Vs
        {
            const int row = tid >> 2, seg = tid & 3;
            const ushort* gk = &k[(size_t)(t0 + row) * ldk + kvh * HD_ + seg * 16];
            u16x8 k0v = *(const u16x8*)gk;
            u16x8 k1v = *(const u16x8*)(gk + 8);
            const ushort* gv = &vt[(size_t)(kvh * HD_ + row) * TOT_ + t0 + seg * 16];
            u16x8 v0v = *(const u16x8*)gv;
            u16x8 v1v = *(const u16x8*)(gv + 8);
            *(u16x8*)&Ks[row * LDT + seg * 16]     = k0v;
            *(u16x8*)&Ks[row * LDT + seg * 16 + 8] = k1v;
            *(u16x8*)&Vs[row * LDT + seg * 16]     = v0v;
            *(u16x8*)&Vs[row * LDT + seg * 16 + 8] = v1v;
        }
        __syncthreads();

        // ---- S^T = K·Q^T : st[nt][r] = S[qrow=fr][key=nt*16+fq*4+r] ----
        f32x4 st[4];
#pragma unroll
        for (int nt = 0; nt < 4; nt++) {
            bf16x8 a0 = *(const bf16x8*)&Ks[(nt * 16 + fr) * LDT + fq * 8];
            bf16x8 a1 = *(const bf16x8*)&Ks[(nt * 16 + fr) * LDT + 32 + fq * 8];
            f32x4 t = (f32x4){0.f, 0.f, 0.f, 0.f};
            t = __builtin_amdgcn_mfma_f32_16x16x32_bf16(a0, bq0, t, 0, 0, 0);
            t = __builtin_amdgcn_mfma_f32_16x16x32_bf16(a1, bq1, t, 0, 0, 0);
            st[nt] = t;
        }

        // ---- per-lane online softmax (row fr; keys split across fq) ----
        float mt = st[0][0];
#pragma unroll
        for (int nt = 0; nt < 4; nt++)
#pragma unroll
            for (int r = 0; r < 4; r++) mt = fmaxf(mt, st[nt][r]);
        mt = fmaxf(mt, __shfl_xor(mt, 16));
        mt = fmaxf(mt, __shfl_xor(mt, 32));
        const float mn = fmaxf(m, mt);
        const float alpha = exp2f(m - mn);
        m = mn;
        float ss = 0.f;
#pragma unroll
        for (int nt = 0; nt < 4; nt++)
#pragma unroll
            for (int r = 0; r < 4; r++) {
                const float pv = exp2f(st[nt][r] - mn);
                st[nt][r] = pv;
                ss += pv;
            }
        ss += __shfl_xor(ss, 16);
        ss += __shfl_xor(ss, 32);
        l = l * alpha + ss;

        // ---- P -> LDS, 4x b64 (keys contiguous per lane) ----
#pragma unroll
        for (int nt = 0; nt < 4; nt++) {
            ushort4 pk = {f2bf(st[nt][0]), f2bf(st[nt][1]),
                          f2bf(st[nt][2]), f2bf(st[nt][3])};
            *(ushort4*)&Ps[(w * 16 + fr) * LDT + nt * 16 + fq * 4] = pk;
        }

        // ---- PV: O += P·V (A=P rows, B=V^T) ----
        bf16x8 ap0 = *(const bf16x8*)&Ps[(w * 16 + fr) * LDT + fq * 8];
        bf16x8 ap1 = *(const bf16x8*)&Ps[(w * 16 + fr) * LDT + 32 + fq * 8];
        float ar[4];
#pragma unroll
        for (int r = 0; r < 4; r++) ar[r] = __shfl(alpha, fq * 4 + r, 16);
#pragma unroll
        for (int nt = 0; nt < 4; nt++) {
            bf16x8 b0 = *(const bf16x8*)&Vs[(nt * 16 + fr) * LDT + fq * 8];
            bf16x8 b1 = *(const bf16x8*)&Vs[(nt * 16 + fr) * LDT + 32 + fq * 8];
            f32x4 t = acc[nt];
            t[0] *= ar[0]; t[1] *= ar[1]; t[2] *= ar[2]; t[3] *= ar[3];
            t = __builtin_amdgcn_mfma_f32_16x16x32_bf16(ap0, b0, t, 0, 0, 0);
            t = __builtin_amdgcn_mfma_f32_16x16x32_bf16(ap1, b1, t, 0, 0, 0);
            acc[nt] = t;
        }
    }

    // ---- epilogue: unnormalized partial + (m,l) out ----
    float* pz = attp + (size_t)z * COMP_ * H_;
#pragma unroll
    for (int r = 0; r < 4; r++) {
        const int row = q0 + w * 16 + fq * 4 + r;
#pragma unroll
        for (int nt = 0; nt < 4; nt++)
            pz[(size_t)row * H_ + h * HD_ + nt * 16 + fr] = acc[nt][r];
    }
    if (lane < 16)   // fq == 0 lanes hold state for row fr = lane
        ((float2*)ml)[((size_t)z * NH_ + h) * COMP_ + (q0 + w * 16 + fr)] =
            make_float2(m, l);
}

// ---------------------------------------------------------------------------
// Merge the SP_ KV-splits: o = (sum_z a_z * attp_z) / (sum_z a_z * l_z),
// a_z = 2^(m_z - M). n4 = COMP_*H_/4.
// ---------------------------------------------------------------------------
__global__ __launch_bounds__(256) void attn_merge(
    const float* __restrict__ attp, const float* __restrict__ ml,
    ushort* __restrict__ o, int n4)
{
    constexpr int H4 = H_ / 4;
    constexpr size_t PS = (size_t)COMP_ * H_;
    int i = blockIdx.x * 256 + threadIdx.x;
    const int stride = gridDim.x * 256;
    for (; i < n4; i += stride) {
        const int row = i / H4;
        const int col = (i - row * H4) * 4;
        const int h = col >> 6;          // HD_ = 64
        const float2 ml0 = ((const float2*)ml)[((size_t)0 * NH_ + h) * COMP_ + row];
        const float2 ml1 = ((const float2*)ml)[((size_t)1 * NH_ + h) * COMP_ + row];
        const float M = fmaxf(ml0.x, ml1.x);
        const float a0 = exp2f(ml0.x - M), a1 = exp2f(ml1.x - M);
        const float inv = 1.0f / (a0 * ml0.y + a1 * ml1.y);
        const float4 p0 = ((const float4*)attp)[i];
        const float4 p1 = ((const float4*)(attp + PS))[i];
        ushort4 r = {f2bf((a0 * p0.x + a1 * p1.x) * inv),
                     f2bf((a0 * p0.y + a1 * p1.y) * inv),
                     f2bf((a0 * p0.z + a1 * p1.z) * inv),
                     f2bf((a0 * p0.w + a1 * p1.w) * inv)};
        ((ushort4*)o)[i] = r;
    }
}

// ---------------------------------------------------------------------------
// RMSNorm, dual fp32 + bf16 output. One block (256 threads) per row.
// ---------------------------------------------------------------------------
__global__ __launch_bounds__(256) void rmsnorm_dual_k(
    const float* __restrict__ x, const float* __restrict__ w,
    float* __restrict__ y, ushort* __restrict__ yb)
{
    const int row = blockIdx.x;
    const float* xr = x + (size_t)row * H_;
    __shared__ float red[256];

    float s = 0.f;
#pragma unroll
    for (int i = 0; i < 8; i++) {
        const float v = xr[threadIdx.x + i * 256];
        s += v * v;
    }
    red[threadIdx.x] = s;
    __syncthreads();
    for (int t = 128; t > 0; t >>= 1) {
        if (threadIdx.x < t) red[threadIdx.x] += red[threadIdx.x + t];
        __syncthreads();
    }
    const float scale = rsqrtf(red[0] * (1.0f / H_) + EPS_);
#pragma unroll
    for (int i = 0; i < 8; i++) {
        const int idx = threadIdx.x + i * 256;
        const float v = xr[idx] * scale * w[idx];
        y[(size_t)row * H_ + idx] = v;
        yb[(size_t)row * H_ + idx] = f2bf(v);
    }
}

// ---------------------------------------------------------------------------
// Fused-gate/up silu-mul: g_out[row][c] = silu(gu[row][c]) * gu[row][FF+c].
// ---------------------------------------------------------------------------
__global__ __launch_bounds__(256) void silu_mul_gu(
    const ushort* __restrict__ gu, ushort* __restrict__ g, int n4)
{
    constexpr int FF4 = FF_ / 4;
    int i = blockIdx.x * 256 + threadIdx.x;
    const int stride = gridDim.x * 256;
    for (; i < n4; i += stride) {
        const int row = i / FF4;
        const int c = (i - row * FF4) * 4;
        ushort4 gv = *(const ushort4*)&gu[(size_t)row * GU2_ + c];
        ushort4 uv = *(const ushort4*)&gu[(size_t)row * GU2_ + FF_ + c];
        float x0 = bf2f(gv.x), x1 = bf2f(gv.y), x2 = bf2f(gv.z), x3 = bf2f(gv.w);
        x0 = x0 / (1.f + __expf(-x0)) * bf2f(uv.x);
        x1 = x1 / (1.f + __expf(-x1)) * bf2f(uv.y);
        x2 = x2 / (1.f + __expf(-x2)) * bf2f(uv.z);
        x3 = x3 / (1.f + __expf(-x3)) * bf2f(uv.w);
        ushort4 r = {f2bf(x0), f2bf(x1), f2bf(x2), f2bf(x3)};
        ((ushort4*)g)[i] = r;
    }
}

// ---------------------------------------------------------------------------
extern "C" void kernel_launch(void* const* d_in, const int* in_sizes, int n_in,
                              void* d_out, int out_size, void* d_ws, size_t ws_size,
                              hipStream_t stream)
{
    (void)in_sizes; (void)n_in; (void)out_size; (void)ws_size;

    const float* hidden      = (const float*)d_in[0];
    const float* comp_w      = (const float*)d_in[1];
    const float* comp_b      = (const float*)d_in[2];
    const float* q_w         = (const float*)d_in[3];
    const float* k_w         = (const float*)d_in[4];
    const float* v_w         = (const float*)d_in[5];
    const float* o_w         = (const float*)d_in[6];
    const float* attn_norm_w = (const float*)d_in[7];
    const float* mlp_norm_w  = (const float*)d_in[8];
    const float* gate_w      = (const float*)d_in[9];
    const float* up_w        = (const float*)d_in[10];
    const float* down_w      = (const float*)d_in[11];
    float* out = (float*)d_out;

    char* p = (char*)d_ws;
    auto alloc = [&](size_t bytes) -> char* {
        char* r = p; p += (bytes + 255) & ~(size_t)255; return r;
    };
    // bf16 weights (kv and gate/up fused = stacked rows)
    ushort* qw_bf    = (ushort*)alloc((size_t)H_ * H_ * 2);
    ushort* kvw_bf   = (ushort*)alloc((size_t)KV2_ * H_ * 2);
    ushort* ow_bf    = (ushort*)alloc((size_t)H_ * H_ * 2);
    ushort* guw_bf   = (ushort*)alloc((size_t)GU2_ * H_ * 2);
    ushort* down_bf  = (ushort*)alloc((size_t)H_ * FF_ * 2);
    ushort* compw_bf = (ushort*)alloc((size_t)COMP_ * S_ * 2);
    // bf16 activation buffers
    ushort* hidcomp  = (ushort*)alloc((size_t)TOT_ * H_ * 2);   // [hidden; compressed]
    ushort* hidT     = (ushort*)alloc((size_t)H_ * S_ * 2);
    ushort* ct_bf    = (ushort*)alloc((size_t)COMP_ * H_ * 2);
    ushort* ct2_bf   = (ushort*)alloc((size_t)COMP_ * H_ * 2);
    ushort* ob_bf    = (ushort*)alloc((size_t)COMP_ * H_ * 2);
    ushort* qb_bf    = (ushort*)alloc((size_t)COMP_ * H_ * 2);
    ushort* kvb_bf   = (ushort*)alloc((size_t)TOT_ * KV2_ * 2); // k cols 0..511, v cols 512..1023
    ushort* vt_bf    = (ushort*)alloc((size_t)KV_ * TOT_ * 2);
    ushort* gb_bf    = (ushort*)alloc((size_t)COMP_ * FF_ * 2);
    // fp32 activations (residual chain)
    float* comp0 = (float*)alloc((size_t)COMP_ * H_ * 4);
    float* comp1 = (float*)alloc((size_t)COMP_ * H_ * 4);
    float* ct    = (float*)alloc((size_t)COMP_ * H_ * 4);
    float* ct2   = (float*)alloc((size_t)COMP_ * H_ * 4);
    // split-K scratch; time-shared with gate|up C and attention partials
    float*  skbuf = (float*)alloc((size_t)SK_ * TOT_ * KV2_ * 4);
    ushort* gub   = (ushort*)skbuf;                       // (COMP_, GU2_) bf16
    float*  attp  = skbuf;                                // SP_ x (COMP_, H_) fp32 = 16 MB
    float*  mlbuf = skbuf + (size_t)SP_ * COMP_ * H_;     // SP_*NH_*COMP_ float2

    ushort* cur_bf = hidcomp + (size_t)S_ * H_;   // compressed rows of hidcomp

    const dim3 blk(256);

    // ---- one-time converts ----
    f2b_k<<<512, blk, 0, stream>>>(q_w,    qw_bf,            H_ * H_ / 4);
    f2b_k<<<512, blk, 0, stream>>>(k_w,    kvw_bf,           KV_ * H_ / 4);
    f2b_k<<<512, blk, 0, stream>>>(v_w,    kvw_bf + (size_t)KV_ * H_, KV_ * H_ / 4);
    f2b_k<<<512, blk, 0, stream>>>(o_w,    ow_bf,            H_ * H_ / 4);
    f2b_k<<<512, blk, 0, stream>>>(gate_w, guw_bf,           FF_ * H_ / 4);
    f2b_k<<<512, blk, 0, stream>>>(up_w,   guw_bf + (size_t)FF_ * H_, FF_ * H_ / 4);
    f2b_k<<<512, blk, 0, stream>>>(down_w, down_bf,          H_ * FF_ / 4);
    f2b_k<<<512, blk, 0, stream>>>(comp_w, compw_bf,         COMP_ * S_ / 4);
    f2b_k<<<512, blk, 0, stream>>>(hidden, hidcomp,          S_ * H_ / 4);
    tpose64<<<dim3(S_ / 64, H_ / 64), blk, 0, stream>>>(hidcomp, hidT, S_, H_, H_);

    // compressed = comp_w @ hidden + comp_b  (split-K via B = hid^T)
    mfma_gemm_sk<<<dim3(H_ / 128, COMP_ / 128, SK_), blk, 0, stream>>>(
        compw_bf, hidT, skbuf, COMP_, H_, S_, S_ / SK_);
    sk_reduce<<<1024, blk, 0, stream>>>(
        skbuf, COMP_ * H_ / 4, H_ / 4, comp_b, nullptr, 1.f, comp0, cur_bf);

    float* cur = comp0;
    for (int d = 0; d < 2; d++) {
        rmsnorm_dual_k<<<COMP_, blk, 0, stream>>>(cur, attn_norm_w, ct, ct_bf);

        // q = (log2e/8) * (ct @ q_w^T)   [split-K; exp2-domain scaling]
        mfma_gemm_sk<<<dim3(H_ / 128, COMP_ / 128, SK_), blk, 0, stream>>>(
            ct_bf, qw_bf, skbuf, COMP_, H_, H_, H_ / SK_);
        sk_reduce<<<1024, blk, 0, stream>>>(
            skbuf, COMP_ * H_ / 4, H_ / 4, nullptr, nullptr, 0.125f * LOG2E_,
            nullptr, qb_bf);

        // k|v = [hidden; compressed] @ [k_w; v_w]^T   [split-K, fused]
        mfma_gemm_sk<<<dim3(KV2_ / 128, TOT_ / 128, SK_), blk, 0, stream>>>(
            hidcomp, kvw_bf, skbuf, TOT_, KV2_, H_, H_ / SK_);
        sk_reduce<<<1024, blk, 0, stream>>>(
            skbuf, TOT_ * KV2_ / 4, KV2_ / 4, nullptr, nullptr, 1.f, nullptr, kvb_bf);

        // vt = transpose of v half (row-stride KV2_)
        tpose64<<<dim3(TOT_ / 64, KV_ / 64), blk, 0, stream>>>(
            kvb_bf + KV_, vt_bf, TOT_, KV_, KV2_);

        // attention (MFMA flash, S^T formulation, KV-split) + merge
        attn_mfma<<<dim3(COMP_ / 64, NH_, SP_), blk, 0, stream>>>(
            qb_bf, kvb_bf, KV2_, vt_bf, attp, mlbuf);
        attn_merge<<<512, blk, 0, stream>>>(attp, mlbuf, ob_bf, COMP_ * H_ / 4);

        // compressed = o @ o_w^T + ct   [split-K]
        mfma_gemm_sk<<<dim3(H_ / 128, COMP_ / 128, SK_), blk, 0, stream>>>(
            ob_bf, ow_bf, skbuf, COMP_, H_, H_, H_ / SK_);
        sk_reduce<<<1024, blk, 0, stream>>>(
            skbuf, COMP_ * H_ / 4, H_ / 4, nullptr, ct, 1.f, comp1, nullptr);

        rmsnorm_dual_k<<<COMP_, blk, 0, stream>>>(comp1, mlp_norm_w, ct2, ct2_bf);

        // gate|up fused — 256x256 8-phase counted-vmcnt GEMM (176 blocks x 512)
        gemm8ph<<<dim3((GU2_ / 256) * (COMP_ / 256)), dim3(512), 0, stream>>>(
            ct2_bf, guw_bf, gub, GU2_, H_);

        silu_mul_gu<<<1024, blk, 0, stream>>>(gub, gb_bf, COMP_ * FF_ / 4);

        // compressed = g @ down_w^T + ct2   [split-K, Kc = 1408]
        float* dst = (d == 1) ? out : comp0;
        ushort* dst_bf = (d == 1) ? nullptr : cur_bf;
        mfma_gemm_sk<<<dim3(H_ / 128, COMP_ / 128, SK_), blk, 0, stream>>>(
            gb_bf, down_bf, skbuf, COMP_, H_, FF_, FF_ / SK_);
        sk_reduce<<<1024, blk, 0, stream>>>(
            skbuf, COMP_ * H_ / 4, H_ / 4, nullptr, ct2, 1.f, dst, dst_bf);
        cur = dst;
    }
}

// Round 2
// 887.610 us; speedup vs baseline: 1.0391x; 1.0299x over previous
//
#include <hip/hip_runtime.h>
#include <math.h>

// Problem constants (Compress_30047591202836)
constexpr int S_   = 2048;
constexpr int H_   = 2048;
constexpr int NH_  = 32;
constexpr int NKV_ = 8;
constexpr int HD_  = 64;
constexpr int GROUPS_ = NH_ / NKV_;     // 4
constexpr int KV_  = NKV_ * HD_;        // 512
constexpr int KV2_ = 2 * KV_;           // 1024 (k|v fused)
constexpr int COMP_ = 1024;             // S * 0.5
constexpr int FF_  = 5632;
constexpr int GU2_ = 2 * FF_;           // 11264 (gate|up fused)
constexpr int TOT_ = S_ + COMP_;        // 3072
constexpr float EPS_ = 1e-6f;
constexpr int SK_ = 4;                  // split-K factor (GEMMs)
constexpr int SP_ = 2;                  // KV-split factor (attention)
constexpr float LOG2E_ = 1.44269504088896340736f;

typedef __attribute__((ext_vector_type(4))) float f32x4;
typedef __attribute__((ext_vector_type(8))) short bf16x8;
typedef __attribute__((ext_vector_type(8))) ushort u16x8;

__device__ __forceinline__ ushort f2bf(float x) {
    union { float f; unsigned u; } v; v.f = x;
    unsigned r = v.u + 0x7fffu + ((v.u >> 16) & 1u);   // RNE
    return (ushort)(r >> 16);
}
__device__ __forceinline__ float bf2f(ushort x) {
    union { unsigned u; float f; } v; v.u = ((unsigned)x) << 16;
    return v.f;
}
// packed fp32 pair -> 2x bf16 in one u32 (T12; no builtin on gfx950)
__device__ __forceinline__ uint cvtpk_bf16(float lo, float hi) {
    uint r;
    asm("v_cvt_pk_bf16_f32 %0, %1, %2" : "=v"(r) : "v"(lo), "v"(hi));
    return r;
}

// ---------------------------------------------------------------------------
// fp32 -> bf16 convert, float4/ushort4 grid-stride. n4 = n/4.
// ---------------------------------------------------------------------------
__global__ __launch_bounds__(256) void f2b_k(
    const float* __restrict__ x, ushort* __restrict__ y, int n4)
{
    int i = blockIdx.x * 256 + threadIdx.x;
    const int stride = gridDim.x * 256;
    for (; i < n4; i += stride) {
        float4 v = ((const float4*)x)[i];
        ushort4 r = {f2bf(v.x), f2bf(v.y), f2bf(v.z), f2bf(v.w)};
        ((ushort4*)y)[i] = r;
    }
}

// ---------------------------------------------------------------------------
// bf16 64x64 tiled transpose: out[(c0+j)*R + r] = in[(r0+r)*ldi + c0+j].
// ---------------------------------------------------------------------------
__global__ __launch_bounds__(256) void tpose64(
    const ushort* __restrict__ in, ushort* __restrict__ out,
    int R, int C, int ldi)
{
    __shared__ ushort T[64][72];
    const int r0 = blockIdx.x * 64, c0 = blockIdx.y * 64;
    const int row = threadIdx.x >> 2, seg = threadIdx.x & 3;

    const ushort* g = &in[(size_t)(r0 + row) * ldi + c0 + seg * 16];
    *(u16x8*)&T[row][seg * 16]     = *(const u16x8*)g;
    *(u16x8*)&T[row][seg * 16 + 8] = *(const u16x8*)(g + 8);
    __syncthreads();

    ushort tmp[16];
#pragma unroll
    for (int j = 0; j < 16; j++) tmp[j] = T[seg * 16 + j][row];
    ushort* go = &out[(size_t)(c0 + row) * R + r0 + seg * 16];
    *(u16x8*)go       = *(const u16x8*)&tmp[0];
    *(u16x8*)(go + 8) = *(const u16x8*)&tmp[8];
}

// ---------------------------------------------------------------------------
// bf16 MFMA GEMM (non-split): C = oscale*(A@B^T)+bias+addp -> outf/outb.
// 128x128 tile, BK=32, 4 waves, 4x4 mfma_f32_16x16x32_bf16 per wave.
// (kept as fallback; no longer used for gate|up)
// ---------------------------------------------------------------------------
__global__ __launch_bounds__(256) void mfma_gemm(
    const ushort* __restrict__ A, const ushort* __restrict__ B,
    const float* __restrict__ addp, const float* __restrict__ bias,
    float oscale, float* __restrict__ outf, ushort* __restrict__ outb,
    int M, int N, int K)
{
    __shared__ ushort Alds[128 * 32];
    __shared__ ushort Blds[128 * 32];

    const int tid  = threadIdx.x;
    const int w    = tid >> 6;
    const int lane = tid & 63;
    const int bm = blockIdx.y, bn = blockIdx.x;
    const int wr = w >> 1, wc = w & 1;
    const int fr = lane & 15;
    const int fq = lane >> 4;
    const int srow = lane >> 2;
    const int skof = (lane & 3) * 8;

    f32x4 acc[4][4];
#pragma unroll
    for (int i = 0; i < 4; i++)
#pragma unroll
        for (int j = 0; j < 4; j++)
            acc[i][j] = (f32x4){0.f, 0.f, 0.f, 0.f};

    for (int k0 = 0; k0 < K; k0 += 32) {
        __syncthreads();
#pragma unroll
        for (int i = 0; i < 2; i++) {
            const int slot = w * 2 + i;
            const ushort* ga = &A[(size_t)(bm * 128 + slot * 16 + srow) * K + k0 + skof];
            __builtin_amdgcn_global_load_lds(
                (const __attribute__((address_space(1))) void*)ga,
                (__attribute__((address_space(3))) void*)&Alds[slot * 512], 16, 0, 0);
            const ushort* gb = &B[(size_t)(bn * 128 + slot * 16 + srow) * K + k0 + skof];
            __builtin_amdgcn_global_load_lds(
                (const __attribute__((address_space(1))) void*)gb,
                (__attribute__((address_space(3))) void*)&Blds[slot * 512], 16, 0, 0);
        }
        __syncthreads();

        bf16x8 a[4], b[4];
#pragma unroll
        for (int mt = 0; mt < 4; mt++)
            a[mt] = *(const bf16x8*)&Alds[(wr * 64 + mt * 16 + fr) * 32 + fq * 8];
#pragma unroll
        for (int nt = 0; nt < 4; nt++)
            b[nt] = *(const bf16x8*)&Blds[(wc * 64 + nt * 16 + fr) * 32 + fq * 8];

#pragma unroll
        for (int mt = 0; mt < 4; mt++)
#pragma unroll
            for (int nt = 0; nt < 4; nt++)
                acc[mt][nt] = __builtin_amdgcn_mfma_f32_16x16x32_bf16(
                    a[mt], b[nt], acc[mt][nt], 0, 0, 0);
    }

#pragma unroll
    for (int mt = 0; mt < 4; mt++) {
#pragma unroll
        for (int nt = 0; nt < 4; nt++) {
#pragma unroll
            for (int r = 0; r < 4; r++) {
                const int row = bm * 128 + wr * 64 + mt * 16 + fq * 4 + r;
                const int col = bn * 128 + wc * 64 + nt * 16 + fr;
                float v = acc[mt][nt][r] * oscale;
                if (bias) v += bias[row];
                if (addp) v += addp[(size_t)row * N + col];
                if (outf) outf[(size_t)row * N + col] = v;
                if (outb) outb[(size_t)row * N + col] = f2bf(v);
            }
        }
    }
}

// ---------------------------------------------------------------------------
// 256x256-tile 8-phase counted-vmcnt bf16 GEMM (guide §5 template, plain HIP).
// (unchanged this round; counters pending once it surfaces in top-5)
// ---------------------------------------------------------------------------
#define BARS do { __builtin_amdgcn_s_barrier(); __builtin_amdgcn_sched_barrier(0); } while (0)
#define VMW(n) asm volatile("s_waitcnt vmcnt(" #n ")" ::: "memory")
#define STG(gp, lp) __builtin_amdgcn_global_load_lds( \
    (const __attribute__((address_space(1))) void*)(gp), \
    (__attribute__((address_space(3))) void*)(lp), 16, 0, 0)
#define STA(bufA, R0, kt) STG(Ag + (size_t)(R0) * K + (kt) * 64, &(bufA)[((R0) + w * 8) * 64])
#define STB(bufB, R0, kt) STG(Bg + (size_t)(R0) * K + (kt) * 64, &(bufB)[((R0) + w * 8) * 64])

__device__ __forceinline__ void ldaq(bf16x8 (&aa)[2][2], const ushort* bufA,
                                     int m0, int aoff, int s0, int s1)
{
#pragma unroll
    for (int m = 0; m < 2; m++) {
        aa[m][0] = *(const bf16x8*)&bufA[aoff + (m0 + m) * 1024 + s0];
        aa[m][1] = *(const bf16x8*)&bufA[aoff + (m0 + m) * 1024 + s1];
    }
}
__device__ __forceinline__ void ldbq(bf16x8 (&bb)[4][2], const ushort* bufB,
                                     int boff, int s0, int s1)
{
#pragma unroll
    for (int nt = 0; nt < 4; nt++) {
        bb[nt][0] = *(const bf16x8*)&bufB[boff + nt * 1024 + s0];
        bb[nt][1] = *(const bf16x8*)&bufB[boff + nt * 1024 + s1];
    }
}
template <int M0>
__device__ __forceinline__ void mfmaq(f32x4 (&acc)[8][4], bf16x8 (&aa)[2][2],
                                      bf16x8 (&bb)[4][2])
{
    __builtin_amdgcn_s_setprio(1);
#pragma unroll
    for (int m = 0; m < 2; m++)
#pragma unroll
        for (int nt = 0; nt < 4; nt++) {
            acc[M0 + m][nt] = __builtin_amdgcn_mfma_f32_16x16x32_bf16(
                aa[m][0], bb[nt][0], acc[M0 + m][nt], 0, 0, 0);
            acc[M0 + m][nt] = __builtin_amdgcn_mfma_f32_16x16x32_bf16(
                aa[m][1], bb[nt][1], acc[M0 + m][nt], 0, 0, 0);
        }
    __builtin_amdgcn_s_setprio(0);
}

__global__ __launch_bounds__(512, 2) void gemm8ph(
    const ushort* __restrict__ A, const ushort* __restrict__ B,
    ushort* __restrict__ C, int N, int K)
{
    alignas(16) __shared__ ushort lds[4][16384];   // A0,B0,A1,B1 (32 KiB each)
    ushort* const lA0 = lds[0];
    ushort* const lB0 = lds[1];
    ushort* const lA1 = lds[2];
    ushort* const lB1 = lds[3];

    const int tid = threadIdx.x;
    const int w = tid >> 6, lane = tid & 63;
    const int wr = w >> 2, wc = w & 3;
    const int fr = lane & 15, fq = lane >> 4;
    const int xk = fr & 7;

    const int nwg = gridDim.x;
    const int nbn = N >> 8;
    int id = (int)blockIdx.x;
    if (!(nwg & 7)) id = (id & 7) * (nwg >> 3) + (id >> 3);
    const int bm = id / nbn, bn = id - bm * nbn;

    const int srow = lane >> 3;
    const int scol = ((lane & 7) ^ srow) << 3;     // elements
    const ushort* Ag = A + (size_t)(bm * 256 + w * 8 + srow) * K + scol;
    const ushort* Bg = B + (size_t)(bn * 256 + w * 8 + srow) * K + scol;

    const int aoff = (wr * 128 + fr) * 64;
    const int boff = (wc * 64 + fr) * 64;
    const int s0 = ((0 + fq) ^ xk) << 3;           // kk=0 slot, elements
    const int s1 = ((4 + fq) ^ xk) << 3;           // kk=1 slot

    f32x4 acc[8][4];
#pragma unroll
    for (int i = 0; i < 8; i++)
#pragma unroll
        for (int j = 0; j < 4; j++) acc[i][j] = (f32x4){0.f, 0.f, 0.f, 0.f};

    bf16x8 aa[2][2], bb[4][2];

    STB(lB0, 0, 0);   STB(lB0, 64, 0);
    STA(lA0, 0, 0);   STA(lA0, 128, 0);
    STB(lB0, 128, 0); STB(lB0, 192, 0);
    STA(lA0, 64, 0);  STA(lA0, 192, 0);
    STB(lB1, 0, 1);   STB(lB1, 64, 1);
    STA(lA1, 0, 1);   STA(lA1, 128, 1);
    STB(lB1, 128, 1); STB(lB1, 192, 1);
    VMW(6);
    BARS;

    const int NITER = K >> 7;          // pairs of BK=64 tiles
    for (int i = 0; i < NITER - 1; i++) {
        const int t1 = 2 * i + 1, t2 = 2 * i + 2, t3 = 2 * i + 3;
        ldbq(bb, lB0, boff, s0, s1);
        ldaq(aa, lA0, 0, aoff, s0, s1);
        STA(lA1, 64, t1); STA(lA1, 192, t1);
        BARS; mfmaq<0>(acc, aa, bb); BARS;
        ldaq(aa, lA0, 2, aoff, s0, s1);
        STB(lB0, 0, t2); STB(lB0, 64, t2);
        BARS; mfmaq<2>(acc, aa, bb); BARS;
        ldaq(aa, lA0, 4, aoff, s0, s1);
        STA(lA0, 0, t2); STA(lA0, 128, t2);
        BARS; mfmaq<4>(acc, aa, bb); BARS;
        ldaq(aa, lA0, 6, aoff, s0, s1);
        STB(lB0, 128, t2); STB(lB0, 192, t2);
        BARS; mfmaq<6>(acc, aa, bb); VMW(6); BARS;
        ldbq(bb, lB1, boff, s0, s1);
        ldaq(aa, lA1, 0, aoff, s0, s1);
        STA(lA0, 64, t2); STA(lA0, 192, t2);
        BARS; mfmaq<0>(acc, aa, bb); BARS;
        ldaq(aa, lA1, 2, aoff, s0, s1);
        STB(lB1, 0, t3); STB(lB1, 64, t3);
        BARS; mfmaq<2>(acc, aa, bb); BARS;
        ldaq(aa, lA1, 4, aoff, s0, s1);
        STA(lA1, 0, t3); STA(lA1, 128, t3);
        BARS; mfmaq<4>(acc, aa, bb); BARS;
        ldaq(aa, lA1, 6, aoff, s0, s1);
        STB(lB1, 128, t3); STB(lB1, 192, t3);
        BARS; mfmaq<6>(acc, aa, bb); VMW(6); BARS;
    }
    {
        const int t1 = 2 * NITER - 1;
        ldbq(bb, lB0, boff, s0, s1);
        ldaq(aa, lA0, 0, aoff, s0, s1);
        STA(lA1, 64, t1); STA(lA1, 192, t1);
        BARS; mfmaq<0>(acc, aa, bb); BARS;
        ldaq(aa, lA0, 2, aoff, s0, s1);
        BARS; mfmaq<2>(acc, aa, bb); BARS;
        ldaq(aa, lA0, 4, aoff, s0, s1);
        BARS; mfmaq<4>(acc, aa, bb); BARS;
        ldaq(aa, lA0, 6, aoff, s0, s1);
        BARS; mfmaq<6>(acc, aa, bb); VMW(0); BARS;
        ldbq(bb, lB1, boff, s0, s1);
        ldaq(aa, lA1, 0, aoff, s0, s1);
        BARS; mfmaq<0>(acc, aa, bb); BARS;
        ldaq(aa, lA1, 2, aoff, s0, s1);
        BARS; mfmaq<2>(acc, aa, bb); BARS;
        ldaq(aa, lA1, 4, aoff, s0, s1);
        BARS; mfmaq<4>(acc, aa, bb); BARS;
        ldaq(aa, lA1, 6, aoff, s0, s1);
        mfmaq<6>(acc, aa, bb);
    }

    ushort* Cb = C + (size_t)(bm * 256 + wr * 128 + fq * 4) * N
                   + bn * 256 + wc * 64 + fr;
#pragma unroll
    for (int mt = 0; mt < 8; mt++)
#pragma unroll
        for (int nt = 0; nt < 4; nt++)
#pragma unroll
            for (int r = 0; r < 4; r++)
                Cb[(size_t)(mt * 16 + r) * N + nt * 16] = f2bf(acc[mt][nt][r]);
}

// ---------------------------------------------------------------------------
// Split-K MFMA GEMM: grid.z = SK slices of K. Raw fp32 partials to part.
// ---------------------------------------------------------------------------
__global__ __launch_bounds__(256) void mfma_gemm_sk(
    const ushort* __restrict__ A, const ushort* __restrict__ B,
    float* __restrict__ part, int M, int N, int K, int Kc)
{
    __shared__ ushort Alds[128 * 32];
    __shared__ ushort Blds[128 * 32];

    const int tid  = threadIdx.x;
    const int w    = tid >> 6;
    const int lane = tid & 63;
    const int bm = blockIdx.y, bn = blockIdx.x, z = blockIdx.z;
    const int wr = w >> 1, wc = w & 1;
    const int fr = lane & 15;
    const int fq = lane >> 4;
    const int srow = lane >> 2;
    const int skof = (lane & 3) * 8;

    f32x4 acc[4][4];
#pragma unroll
    for (int i = 0; i < 4; i++)
#pragma unroll
        for (int j = 0; j < 4; j++)
            acc[i][j] = (f32x4){0.f, 0.f, 0.f, 0.f};

    const int kbeg = z * Kc;
    for (int k0 = kbeg; k0 < kbeg + Kc; k0 += 32) {
        __syncthreads();
#pragma unroll
        for (int i = 0; i < 2; i++) {
            const int slot = w * 2 + i;
            const ushort* ga = &A[(size_t)(bm * 128 + slot * 16 + srow) * K + k0 + skof];
            __builtin_amdgcn_global_load_lds(
                (const __attribute__((address_space(1))) void*)ga,
                (__attribute__((address_space(3))) void*)&Alds[slot * 512], 16, 0, 0);
            const ushort* gb = &B[(size_t)(bn * 128 + slot * 16 + srow) * K + k0 + skof];
            __builtin_amdgcn_global_load_lds(
                (const __attribute__((address_space(1))) void*)gb,
                (__attribute__((address_space(3))) void*)&Blds[slot * 512], 16, 0, 0);
        }
        __syncthreads();

        bf16x8 a[4], b[4];
#pragma unroll
        for (int mt = 0; mt < 4; mt++)
            a[mt] = *(const bf16x8*)&Alds[(wr * 64 + mt * 16 + fr) * 32 + fq * 8];
#pragma unroll
        for (int nt = 0; nt < 4; nt++)
            b[nt] = *(const bf16x8*)&Blds[(wc * 64 + nt * 16 + fr) * 32 + fq * 8];

#pragma unroll
        for (int mt = 0; mt < 4; mt++)
#pragma unroll
            for (int nt = 0; nt < 4; nt++)
                acc[mt][nt] = __builtin_amdgcn_mfma_f32_16x16x32_bf16(
                    a[mt], b[nt], acc[mt][nt], 0, 0, 0);
    }

    float* pz = part + (size_t)z * M * N;
#pragma unroll
    for (int mt = 0; mt < 4; mt++)
#pragma unroll
        for (int nt = 0; nt < 4; nt++)
#pragma unroll
            for (int r = 0; r < 4; r++) {
                const int row = bm * 128 + wr * 64 + mt * 16 + fq * 4 + r;
                const int col = bn * 128 + wc * 64 + nt * 16 + fr;
                pz[(size_t)row * N + col] = acc[mt][nt][r];
            }
}

// ---------------------------------------------------------------------------
// Split-K reduce + epilogue.
// ---------------------------------------------------------------------------
__global__ __launch_bounds__(256) void sk_reduce(
    const float* __restrict__ part, int mn4, int n4,
    const float* __restrict__ bias, const float* __restrict__ addp,
    float oscale, float* __restrict__ outf, ushort* __restrict__ outb)
{
    const size_t mn = (size_t)mn4 * 4;
    int i = blockIdx.x * 256 + threadIdx.x;
    const int stride = gridDim.x * 256;
    for (; i < mn4; i += stride) {
        float4 v = ((const float4*)part)[i];
#pragma unroll
        for (int z = 1; z < SK_; z++) {
            const float4 pz = ((const float4*)(part + z * mn))[i];
            v.x += pz.x; v.y += pz.y; v.z += pz.z; v.w += pz.w;
        }
        v.x *= oscale; v.y *= oscale; v.z *= oscale; v.w *= oscale;
        if (bias) {
            const float bb = bias[i / n4];
            v.x += bb; v.y += bb; v.z += bb; v.w += bb;
        }
        if (addp) {
            const float4 ad = ((const float4*)addp)[i];
            v.x += ad.x; v.y += ad.y; v.z += ad.z; v.w += ad.w;
        }
        if (outf) ((float4*)outf)[i] = v;
        if (outb) {
            ushort4 r = {f2bf(v.x), f2bf(v.y), f2bf(v.z), f2bf(v.w)};
            ((ushort4*)outb)[i] = r;
        }
    }
}

// ---------------------------------------------------------------------------
// MFMA flash attention v2: KV-split, S^T formulation, lane-linear fragment
// LDS staged via global_load_lds (per-lane pre-permuted GLOBAL source, linear
// LDS dest — rule #21), double-buffered with async stage (T14), cvt_pk P-pack
// (T12), defer-max rescale THR=8 (T13), setprio around MFMA (T5).
//   q : (COMP_, H_) bf16, PRE-SCALED by log2(e)/sqrt(HD)  (exp2 domain)
//   k : fused kv buffer rows, row-stride ldk (k half)
//   vt: (KV_, TOT_) bf16 transposed V
// LDS layout: Kb/Vb chunk (h*4+nt) holds the MFMA fragment for key/d sub-tile
// nt, K-half h, in lane*16B order -> every ds_read_b128 is lane-consecutive
// (conflict-free). Ps [64][64] with both-sides XOR (slot ^= fr&7).
// One barrier + vmcnt(0) per tile. LDS = 16+16+8 = 40 KB (4 blocks/CU).
// ---------------------------------------------------------------------------
__global__ __launch_bounds__(256) void attn_mfma(
    const ushort* __restrict__ q, const ushort* __restrict__ k, int ldk,
    const ushort* __restrict__ vt, float* __restrict__ attp,
    float* __restrict__ ml)
{
    constexpr int KSPAN = TOT_ / SP_;   // 1536 keys per split
    alignas(16) __shared__ ushort Kb[2][8 * 512];   // [buf][(h*4+nt)*512 + lane*8]
    alignas(16) __shared__ ushort Vb[2][8 * 512];
    alignas(16) __shared__ ushort Ps[64 * 64];      // XOR-swizzled

    const int qt = blockIdx.x, h = blockIdx.y, z = blockIdx.z;
    const int kvh = h / GROUPS_;
    const int tid = threadIdx.x;
    const int w = tid >> 6, lane = tid & 63;
    const int fr = lane & 15, fq = lane >> 4;
    const int q0 = qt * 64;

    // Q B-fragments straight from global: B[n=fr][k=fq*8+j] (+32 half)
    const ushort* qrow = &q[(size_t)(q0 + w * 16 + fr) * H_ + h * HD_];
    const bf16x8 bq0 = *(const bf16x8*)(qrow + fq * 8);
    const bf16x8 bq1 = *(const bf16x8*)(qrow + 32 + fq * 8);

    float m = -1e30f, l = 0.f;          // per-lane row state (row = fr)
    f32x4 acc[4];
#pragma unroll
    for (int nt = 0; nt < 4; nt++) acc[nt] = (f32x4){0.f, 0.f, 0.f, 0.f};

    const int t_beg = z * KSPAN;
    // staging source pointers: wave w stages chunks nt=w (both halves) of K,V.
    // K chunk lane map: row = t0 + w*16 + fr, col = kvh*64 + h*32 + fq*8
    // V chunk lane map: d   = kvh*64 + w*16 + fr (vt row), key = t0 + h*32 + fq*8
    const ushort* kp = &k[(size_t)(t_beg + w * 16 + fr) * ldk + kvh * HD_ + fq * 8];
    const ushort* vp = &vt[(size_t)(kvh * HD_ + w * 16 + fr) * TOT_ + t_beg + fq * 8];

#define ASTG(gp, lp) __builtin_amdgcn_global_load_lds( \
    (const __attribute__((address_space(1))) void*)(gp), \
    (__attribute__((address_space(3))) void*)(lp), 16, 0, 0)

    // prologue: stage tile 0 into buf 0
    ASTG(kp,      &Kb[0][w * 512]);
    ASTG(kp + 32, &Kb[0][(4 + w) * 512]);
    ASTG(vp,      &Vb[0][w * 512]);
    ASTG(vp + 32, &Vb[0][(4 + w) * 512]);
    asm volatile("s_waitcnt vmcnt(0)" ::: "memory");
    __syncthreads();
    const ushort* kn = kp + (size_t)64 * ldk;   // next-tile sources
    const ushort* vn = vp + 64;

    const int pxor = (fr & 7) << 4;
    char* const psb = (char*)&Ps[(w * 16 + fr) * 64];

    const int NT = KSPAN / 64;          // 24
    int cur = 0;
    for (int t = 0; t < NT; t++) {
        // ---- S^T = K·Q^T (lane-linear conflict-free fragment reads) ----
        f32x4 st[4];
        __builtin_amdgcn_s_setprio(1);
#pragma unroll
        for (int nt = 0; nt < 4; nt++) {
            const bf16x8 a0 = *(const bf16x8*)&Kb[cur][(nt * 64 + lane) * 8];
            const bf16x8 a1 = *(const bf16x8*)&Kb[cur][((4 + nt) * 64 + lane) * 8];
            f32x4 tacc = (f32x4){0.f, 0.f, 0.f, 0.f};
            tacc = __builtin_amdgcn_mfma_f32_16x16x32_bf16(a0, bq0, tacc, 0, 0, 0);
            tacc = __builtin_amdgcn_mfma_f32_16x16x32_bf16(a1, bq1, tacc, 0, 0, 0);
            st[nt] = tacc;
        }
        __builtin_amdgcn_s_setprio(0);

        // ---- async-stage tile t+1 into the other buffer (T14) ----
        if (t + 1 < NT) {
            ASTG(kn,      &Kb[cur ^ 1][w * 512]);
            ASTG(kn + 32, &Kb[cur ^ 1][(4 + w) * 512]);
            ASTG(vn,      &Vb[cur ^ 1][w * 512]);
            ASTG(vn + 32, &Vb[cur ^ 1][(4 + w) * 512]);
            kn += (size_t)64 * ldk;
            vn += 64;
        }

        // ---- per-lane online softmax (row fr; keys split across fq) ----
        float mt = st[0][0];
#pragma unroll
        for (int nt = 0; nt < 4; nt++)
#pragma unroll
            for (int r = 0; r < 4; r++) mt = fmaxf(mt, st[nt][r]);
        mt = fmaxf(mt, __shfl_xor(mt, 16));
        mt = fmaxf(mt, __shfl_xor(mt, 32));
        if (!__all(mt <= m + 8.0f)) {   // defer-max (T13): rescale only on growth
            const float mnew = fmaxf(m, mt);
            const float alpha = exp2f(m - mnew);
            m = mnew;
            l *= alpha;
            const float ar0 = __shfl(alpha, fq * 4 + 0, 16);
            const float ar1 = __shfl(alpha, fq * 4 + 1, 16);
            const float ar2 = __shfl(alpha, fq * 4 + 2, 16);
            const float ar3 = __shfl(alpha, fq * 4 + 3, 16);
#pragma unroll
            for (int nt = 0; nt < 4; nt++) {
                acc[nt][0] *= ar0; acc[nt][1] *= ar1;
                acc[nt][2] *= ar2; acc[nt][3] *= ar3;
            }
        }
        float ss = 0.f;
#pragma unroll
        for (int nt = 0; nt < 4; nt++)
#pragma unroll
            for (int r = 0; r < 4; r++) {
                const float pv = exp2f(st[nt][r] - m);
                st[nt][r] = pv;
                ss += pv;
            }
        ss += __shfl_xor(ss, 16);
        ss += __shfl_xor(ss, 32);
        l += ss;

        // ---- P -> Ps via cvt_pk (T12), XOR-swizzled 8B stores ----
#pragma unroll
        for (int nt = 0; nt < 4; nt++) {
            uint2 uu;
            uu.x = cvtpk_bf16(st[nt][0], st[nt][1]);
            uu.y = cvtpk_bf16(st[nt][2], st[nt][3]);
            *(uint2*)(psb + ((nt * 32 + fq * 8) ^ pxor)) = uu;
        }
        const bf16x8 ap0 = *(const bf16x8*)(psb + ((fq * 16) ^ pxor));
        const bf16x8 ap1 = *(const bf16x8*)(psb + ((64 + fq * 16) ^ pxor));

        // ---- PV: O += P·V (lane-linear V fragments) ----
        __builtin_amdgcn_s_setprio(1);
#pragma unroll
        for (int nt = 0; nt < 4; nt++) {
            const bf16x8 b0 = *(const bf16x8*)&Vb[cur][(nt * 64 + lane) * 8];
            const bf16x8 b1 = *(const bf16x8*)&Vb[cur][((4 + nt) * 64 + lane) * 8];
            acc[nt] = __builtin_amdgcn_mfma_f32_16x16x32_bf16(ap0, b0, acc[nt], 0, 0, 0);
            acc[nt] = __builtin_amdgcn_mfma_f32_16x16x32_bf16(ap1, b1, acc[nt], 0, 0, 0);
        }
        __builtin_amdgcn_s_setprio(0);

        // ---- tile end: own stages drained, all waves synced ----
        asm volatile("s_waitcnt vmcnt(0)" ::: "memory");
        __syncthreads();
        cur ^= 1;
    }
#undef ASTG

    // ---- epilogue: unnormalized partial + (m,l) out ----
    float* pz = attp + (size_t)z * COMP_ * H_;
#pragma unroll
    for (int r = 0; r < 4; r++) {
        const int row = q0 + w * 16 + fq * 4 + r;
#pragma unroll
        for (int nt = 0; nt < 4; nt++)
            pz[(size_t)row * H_ + h * HD_ + nt * 16 + fr] = acc[nt][r];
    }
    if (lane < 16)   // fq == 0 lanes hold state for row fr = lane
        ((float2*)ml)[((size_t)z * NH_ + h) * COMP_ + (q0 + w * 16 + fr)] =
            make_float2(m, l);
}

// ---------------------------------------------------------------------------
// Merge the SP_ KV-splits: o = (sum_z a_z * attp_z) / (sum_z a_z * l_z),
// a_z = 2^(m_z - M). n4 = COMP_*H_/4.
// ---------------------------------------------------------------------------
__global__ __launch_bounds__(256) void attn_merge(
    const float* __restrict__ attp, const float* __restrict__ ml,
    ushort* __restrict__ o, int n4)
{
    constexpr int H4 = H_ / 4;
    constexpr size_t PS = (size_t)COMP_ * H_;
    int i = blockIdx.x * 256 + threadIdx.x;
    const int stride = gridDim.x * 256;
    for (; i < n4; i += stride) {
        const int row = i / H4;
        const int col = (i - row * H4) * 4;
        const int h = col >> 6;          // HD_ = 64
        const float2 ml0 = ((const float2*)ml)[((size_t)0 * NH_ + h) * COMP_ + row];
        const float2 ml1 = ((const float2*)ml)[((size_t)1 * NH_ + h) * COMP_ + row];
        const float M = fmaxf(ml0.x, ml1.x);
        const float a0 = exp2f(ml0.x - M), a1 = exp2f(ml1.x - M);
        const float inv = 1.0f / (a0 * ml0.y + a1 * ml1.y);
        const float4 p0 = ((const float4*)attp)[i];
        const float4 p1 = ((const float4*)(attp + PS))[i];
        ushort4 r = {f2bf((a0 * p0.x + a1 * p1.x) * inv),
                     f2bf((a0 * p0.y + a1 * p1.y) * inv),
                     f2bf((a0 * p0.z + a1 * p1.z) * inv),
                     f2bf((a0 * p0.w + a1 * p1.w) * inv)};
        ((ushort4*)o)[i] = r;
    }
}

// ---------------------------------------------------------------------------
// RMSNorm, dual fp32 + bf16 output. One block (256 threads) per row.
// ---------------------------------------------------------------------------
__global__ __launch_bounds__(256) void rmsnorm_dual_k(
    const float* __restrict__ x, const float* __restrict__ w,
    float* __restrict__ y, ushort* __restrict__ yb)
{
    const int row = blockIdx.x;
    const float* xr = x + (size_t)row * H_;
    __shared__ float red[256];

    float s = 0.f;
#pragma unroll
    for (int i = 0; i < 8; i++) {
        const float v = xr[threadIdx.x + i * 256];
        s += v * v;
    }
    red[threadIdx.x] = s;
    __syncthreads();
    for (int t = 128; t > 0; t >>= 1) {
        if (threadIdx.x < t) red[threadIdx.x] += red[threadIdx.x + t];
        __syncthreads();
    }
    const float scale = rsqrtf(red[0] * (1.0f / H_) + EPS_);
#pragma unroll
    for (int i = 0; i < 8; i++) {
        const int idx = threadIdx.x + i * 256;
        const float v = xr[idx] * scale * w[idx];
        y[(size_t)row * H_ + idx] = v;
        yb[(size_t)row * H_ + idx] = f2bf(v);
    }
}

// ---------------------------------------------------------------------------
// Fused-gate/up silu-mul: g_out[row][c] = silu(gu[row][c]) * gu[row][FF+c].
// ---------------------------------------------------------------------------
__global__ __launch_bounds__(256) void silu_mul_gu(
    const ushort* __restrict__ gu, ushort* __restrict__ g, int n4)
{
    constexpr int FF4 = FF_ / 4;
    int i = blockIdx.x * 256 + threadIdx.x;
    const int stride = gridDim.x * 256;
    for (; i < n4; i += stride) {
        const int row = i / FF4;
        const int c = (i - row * FF4) * 4;
        ushort4 gv = *(const ushort4*)&gu[(size_t)row * GU2_ + c];
        ushort4 uv = *(const ushort4*)&gu[(size_t)row * GU2_ + FF_ + c];
        float x0 = bf2f(gv.x), x1 = bf2f(gv.y), x2 = bf2f(gv.z), x3 = bf2f(gv.w);
        x0 = x0 / (1.f + __expf(-x0)) * bf2f(uv.x);
        x1 = x1 / (1.f + __expf(-x1)) * bf2f(uv.y);
        x2 = x2 / (1.f + __expf(-x2)) * bf2f(uv.z);
        x3 = x3 / (1.f + __expf(-x3)) * bf2f(uv.w);
        ushort4 r = {f2bf(x0), f2bf(x1), f2bf(x2), f2bf(x3)};
        ((ushort4*)g)[i] = r;
    }
}

// ---------------------------------------------------------------------------
extern "C" void kernel_launch(void* const* d_in, const int* in_sizes, int n_in,
                              void* d_out, int out_size, void* d_ws, size_t ws_size,
                              hipStream_t stream)
{
    (void)in_sizes; (void)n_in; (void)out_size; (void)ws_size;

    const float* hidden      = (const float*)d_in[0];
    const float* comp_w      = (const float*)d_in[1];
    const float* comp_b      = (const float*)d_in[2];
    const float* q_w         = (const float*)d_in[3];
    const float* k_w         = (const float*)d_in[4];
    const float* v_w         = (const float*)d_in[5];
    const float* o_w         = (const float*)d_in[6];
    const float* attn_norm_w = (const float*)d_in[7];
    const float* mlp_norm_w  = (const float*)d_in[8];
    const float* gate_w      = (const float*)d_in[9];
    const float* up_w        = (const float*)d_in[10];
    const float* down_w      = (const float*)d_in[11];
    float* out = (float*)d_out;

    char* p = (char*)d_ws;
    auto alloc = [&](size_t bytes) -> char* {
        char* r = p; p += (bytes + 255) & ~(size_t)255; return r;
    };
    // bf16 weights (kv and gate/up fused = stacked rows)
    ushort* qw_bf    = (ushort*)alloc((size_t)H_ * H_ * 2);
    ushort* kvw_bf   = (ushort*)alloc((size_t)KV2_ * H_ * 2);
    ushort* ow_bf    = (ushort*)alloc((size_t)H_ * H_ * 2);
    ushort* guw_bf   = (ushort*)alloc((size_t)GU2_ * H_ * 2);
    ushort* down_bf  = (ushort*)alloc((size_t)H_ * FF_ * 2);
    ushort* compw_bf = (ushort*)alloc((size_t)COMP_ * S_ * 2);
    // bf16 activation buffers
    ushort* hidcomp  = (ushort*)alloc((size_t)TOT_ * H_ * 2);   // [hidden; compressed]
    ushort* hidT     = (ushort*)alloc((size_t)H_ * S_ * 2);
    ushort* ct_bf    = (ushort*)alloc((size_t)COMP_ * H_ * 2);
    ushort* ct2_bf   = (ushort*)alloc((size_t)COMP_ * H_ * 2);
    ushort* ob_bf    = (ushort*)alloc((size_t)COMP_ * H_ * 2);
    ushort* qb_bf    = (ushort*)alloc((size_t)COMP_ * H_ * 2);
    ushort* kvb_bf   = (ushort*)alloc((size_t)TOT_ * KV2_ * 2); // k cols 0..511, v cols 512..1023
    ushort* vt_bf    = (ushort*)alloc((size_t)KV_ * TOT_ * 2);
    ushort* gb_bf    = (ushort*)alloc((size_t)COMP_ * FF_ * 2);
    // fp32 activations (residual chain)
    float* comp0 = (float*)alloc((size_t)COMP_ * H_ * 4);
    float* comp1 = (float*)alloc((size_t)COMP_ * H_ * 4);
    float* ct    = (float*)alloc((size_t)COMP_ * H_ * 4);
    float* ct2   = (float*)alloc((size_t)COMP_ * H_ * 4);
    // split-K scratch; time-shared with gate|up C and attention partials
    float*  skbuf = (float*)alloc((size_t)SK_ * TOT_ * KV2_ * 4);
    ushort* gub   = (ushort*)skbuf;                       // (COMP_, GU2_) bf16
    float*  attp  = skbuf;                                // SP_ x (COMP_, H_) fp32 = 16 MB
    float*  mlbuf = skbuf + (size_t)SP_ * COMP_ * H_;     // SP_*NH_*COMP_ float2

    ushort* cur_bf = hidcomp + (size_t)S_ * H_;   // compressed rows of hidcomp

    const dim3 blk(256);

    // ---- one-time converts ----
    f2b_k<<<512, blk, 0, stream>>>(q_w,    qw_bf,            H_ * H_ / 4);
    f2b_k<<<512, blk, 0, stream>>>(k_w,    kvw_bf,           KV_ * H_ / 4);
    f2b_k<<<512, blk, 0, stream>>>(v_w,    kvw_bf + (size_t)KV_ * H_, KV_ * H_ / 4);
    f2b_k<<<512, blk, 0, stream>>>(o_w,    ow_bf,            H_ * H_ / 4);
    f2b_k<<<512, blk, 0, stream>>>(gate_w, guw_bf,           FF_ * H_ / 4);
    f2b_k<<<512, blk, 0, stream>>>(up_w,   guw_bf + (size_t)FF_ * H_, FF_ * H_ / 4);
    f2b_k<<<512, blk, 0, stream>>>(down_w, down_bf,          H_ * FF_ / 4);
    f2b_k<<<512, blk, 0, stream>>>(comp_w, compw_bf,         COMP_ * S_ / 4);
    f2b_k<<<512, blk, 0, stream>>>(hidden, hidcomp,          S_ * H_ / 4);
    tpose64<<<dim3(S_ / 64, H_ / 64), blk, 0, stream>>>(hidcomp, hidT, S_, H_, H_);

    // compressed = comp_w @ hidden + comp_b  (split-K via B = hid^T)
    mfma_gemm_sk<<<dim3(H_ / 128, COMP_ / 128, SK_), blk, 0, stream>>>(
        compw_bf, hidT, skbuf, COMP_, H_, S_, S_ / SK_);
    sk_reduce<<<1024, blk, 0, stream>>>(
        skbuf, COMP_ * H_ / 4, H_ / 4, comp_b, nullptr, 1.f, comp0, cur_bf);

    float* cur = comp0;
    for (int d = 0; d < 2; d++) {
        rmsnorm_dual_k<<<COMP_, blk, 0, stream>>>(cur, attn_norm_w, ct, ct_bf);

        // q = (log2e/8) * (ct @ q_w^T)   [split-K; exp2-domain scaling]
        mfma_gemm_sk<<<dim3(H_ / 128, COMP_ / 128, SK_), blk, 0, stream>>>(
            ct_bf, qw_bf, skbuf, COMP_, H_, H_, H_ / SK_);
        sk_reduce<<<1024, blk, 0, stream>>>(
            skbuf, COMP_ * H_ / 4, H_ / 4, nullptr, nullptr, 0.125f * LOG2E_,
            nullptr, qb_bf);

        // k|v = [hidden; compressed] @ [k_w; v_w]^T   [split-K, fused]
        mfma_gemm_sk<<<dim3(KV2_ / 128, TOT_ / 128, SK_), blk, 0, stream>>>(
            hidcomp, kvw_bf, skbuf, TOT_, KV2_, H_, H_ / SK_);
        sk_reduce<<<1024, blk, 0, stream>>>(
            skbuf, TOT_ * KV2_ / 4, KV2_ / 4, nullptr, nullptr, 1.f, nullptr, kvb_bf);

        // vt = transpose of v half (row-stride KV2_)
        tpose64<<<dim3(TOT_ / 64, KV_ / 64), blk, 0, stream>>>(
            kvb_bf + KV_, vt_bf, TOT_, KV_, KV2_);

        // attention (MFMA flash v2, lane-linear frags, async dbuf) + merge
        attn_mfma<<<dim3(COMP_ / 64, NH_, SP_), blk, 0, stream>>>(
            qb_bf, kvb_bf, KV2_, vt_bf, attp, mlbuf);
        attn_merge<<<512, blk, 0, stream>>>(attp, mlbuf, ob_bf, COMP_ * H_ / 4);

        // compressed = o @ o_w^T + ct   [split-K]
        mfma_gemm_sk<<<dim3(H_ / 128, COMP_ / 128, SK_), blk, 0, stream>>>(
            ob_bf, ow_bf, skbuf, COMP_, H_, H_, H_ / SK_);
        sk_reduce<<<1024, blk, 0, stream>>>(
            skbuf, COMP_ * H_ / 4, H_ / 4, nullptr, ct, 1.f, comp1, nullptr);

        rmsnorm_dual_k<<<COMP_, blk, 0, stream>>>(comp1, mlp_norm_w, ct2, ct2_bf);

        // gate|up fused — 256x256 8-phase counted-vmcnt GEMM (176 blocks x 512)
        gemm8ph<<<dim3((GU2_ / 256) * (COMP_ / 256)), dim3(512), 0, stream>>>(
            ct2_bf, guw_bf, gub, GU2_, H_);

        silu_mul_gu<<<1024, blk, 0, stream>>>(gub, gb_bf, COMP_ * FF_ / 4);

        // compressed = g @ down_w^T + ct2   [split-K, Kc = 1408]
        float* dst = (d == 1) ? out : comp0;
        ushort* dst_bf = (d == 1) ? nullptr : cur_bf;
        mfma_gemm_sk<<<dim3(H_ / 128, COMP_ / 128, SK_), blk, 0, stream>>>(
            gb_bf, down_bf, skbuf, COMP_, H_, FF_, FF_ / SK_);
        sk_reduce<<<1024, blk, 0, stream>>>(
            skbuf, COMP_ * H_ / 4, H_ / 4, nullptr, ct2, 1.f, dst, dst_bf);
        cur = dst;
    }
}

// Round 4
// 833.801 us; speedup vs baseline: 1.1061x; 1.0645x over previous
//
#include <hip/hip_runtime.h>
#include <math.h>

// Problem constants (Compress_30047591202836)
constexpr int S_   = 2048;
constexpr int H_   = 2048;
constexpr int NH_  = 32;
constexpr int NKV_ = 8;
constexpr int HD_  = 64;
constexpr int GROUPS_ = NH_ / NKV_;     // 4
constexpr int KV_  = NKV_ * HD_;        // 512
constexpr int KV2_ = 2 * KV_;           // 1024 (k|v fused)
constexpr int COMP_ = 1024;             // S * 0.5
constexpr int FF_  = 5632;
constexpr int GU2_ = 2 * FF_;           // 11264 (gate|up fused, 16-col interleaved)
constexpr int TOT_ = S_ + COMP_;        // 3072
constexpr float EPS_ = 1e-6f;
constexpr int SK_ = 4;                  // split-K factor (GEMMs)
constexpr int SP_ = 2;                  // KV-split factor (attention)
constexpr float LOG2E_ = 1.44269504088896340736f;

typedef __attribute__((ext_vector_type(4))) float f32x4;
typedef __attribute__((ext_vector_type(8))) short bf16x8;
typedef __attribute__((ext_vector_type(8))) ushort u16x8;

__device__ __forceinline__ ushort f2bf(float x) {
    union { float f; unsigned u; } v; v.f = x;
    unsigned r = v.u + 0x7fffu + ((v.u >> 16) & 1u);   // RNE
    return (ushort)(r >> 16);
}
__device__ __forceinline__ float bf2f(ushort x) {
    union { unsigned u; float f; } v; v.u = ((unsigned)x) << 16;
    return v.f;
}
// packed fp32 pair -> 2x bf16 in one u32 (T12; no builtin on gfx950)
__device__ __forceinline__ uint cvtpk_bf16(float lo, float hi) {
    uint r;
    asm("v_cvt_pk_bf16_f32 %0, %1, %2" : "=v"(r) : "v"(lo), "v"(hi));
    return r;
}

// ---------------------------------------------------------------------------
// fp32 -> bf16 convert, float4/ushort4 grid-stride. n4 = n/4.
// ---------------------------------------------------------------------------
__global__ __launch_bounds__(256) void f2b_k(
    const float* __restrict__ x, ushort* __restrict__ y, int n4)
{
    int i = blockIdx.x * 256 + threadIdx.x;
    const int stride = gridDim.x * 256;
    for (; i < n4; i += stride) {
        float4 v = ((const float4*)x)[i];
        ushort4 r = {f2bf(v.x), f2bf(v.y), f2bf(v.z), f2bf(v.w)};
        ((ushort4*)y)[i] = r;
    }
}

// ---------------------------------------------------------------------------
// gate/up fp32 -> bf16 with 16-row interleave: dst row j is
//   gate[srow] if (j>>4)&1==0 else up[srow],  srow = ((j>>5)<<4) | (j&15).
// This makes GEMM output cols alternate gate/up in 16-col blocks so the
// silu-mul is in-lane in the gemm8ph epilogue. n4 = GU2_*H_/4.
// ---------------------------------------------------------------------------
__global__ __launch_bounds__(256) void f2b_gu(
    const float* __restrict__ gate, const float* __restrict__ up,
    ushort* __restrict__ dst, int n4)
{
    constexpr int H4 = H_ / 4;
    int i = blockIdx.x * 256 + threadIdx.x;
    const int stride = gridDim.x * 256;
    for (; i < n4; i += stride) {
        const int j = i / H4, c4 = i - j * H4;
        const float* src = ((j >> 4) & 1) ? up : gate;
        const int srow = ((j >> 5) << 4) | (j & 15);
        const float4 v = ((const float4*)src)[srow * H4 + c4];
        ushort4 r = {f2bf(v.x), f2bf(v.y), f2bf(v.z), f2bf(v.w)};
        ((ushort4*)dst)[i] = r;
    }
}

// ---------------------------------------------------------------------------
// bf16 64x64 tiled transpose: out[(c0+j)*R + r] = in[(r0+r)*ldi + c0+j].
// ---------------------------------------------------------------------------
__global__ __launch_bounds__(256) void tpose64(
    const ushort* __restrict__ in, ushort* __restrict__ out,
    int R, int C, int ldi)
{
    __shared__ ushort T[64][72];
    const int r0 = blockIdx.x * 64, c0 = blockIdx.y * 64;
    const int row = threadIdx.x >> 2, seg = threadIdx.x & 3;

    const ushort* g = &in[(size_t)(r0 + row) * ldi + c0 + seg * 16];
    *(u16x8*)&T[row][seg * 16]     = *(const u16x8*)g;
    *(u16x8*)&T[row][seg * 16 + 8] = *(const u16x8*)(g + 8);
    __syncthreads();

    ushort tmp[16];
#pragma unroll
    for (int j = 0; j < 16; j++) tmp[j] = T[seg * 16 + j][row];
    ushort* go = &out[(size_t)(c0 + row) * R + r0 + seg * 16];
    *(u16x8*)go       = *(const u16x8*)&tmp[0];
    *(u16x8*)(go + 8) = *(const u16x8*)&tmp[8];
}

// ---------------------------------------------------------------------------
// 256x256-tile 8-phase counted-vmcnt bf16 GEMM (guide §5 template), with the
// silu-mul fused into the epilogue: B is the 16-col interleaved gate|up
// weight; acc[mt][even nt]=gate, acc[mt][odd nt]=up for the SAME output col.
//   g[row][c] = silu(gate)*up, c = (bn*8 + wc*2 + u)*16 + fr, g: (M, N/2).
// ---------------------------------------------------------------------------
#define BARS do { __builtin_amdgcn_s_barrier(); __builtin_amdgcn_sched_barrier(0); } while (0)
#define VMW(n) asm volatile("s_waitcnt vmcnt(" #n ")" ::: "memory")
#define STG(gp, lp) __builtin_amdgcn_global_load_lds( \
    (const __attribute__((address_space(1))) void*)(gp), \
    (__attribute__((address_space(3))) void*)(lp), 16, 0, 0)
#define STA(bufA, R0, kt) STG(Ag + (size_t)(R0) * K + (kt) * 64, &(bufA)[((R0) + w * 8) * 64])
#define STB(bufB, R0, kt) STG(Bg + (size_t)(R0) * K + (kt) * 64, &(bufB)[((R0) + w * 8) * 64])

__device__ __forceinline__ void ldaq(bf16x8 (&aa)[2][2], const ushort* bufA,
                                     int m0, int aoff, int s0, int s1)
{
#pragma unroll
    for (int m = 0; m < 2; m++) {
        aa[m][0] = *(const bf16x8*)&bufA[aoff + (m0 + m) * 1024 + s0];
        aa[m][1] = *(const bf16x8*)&bufA[aoff + (m0 + m) * 1024 + s1];
    }
}
__device__ __forceinline__ void ldbq(bf16x8 (&bb)[4][2], const ushort* bufB,
                                     int boff, int s0, int s1)
{
#pragma unroll
    for (int nt = 0; nt < 4; nt++) {
        bb[nt][0] = *(const bf16x8*)&bufB[boff + nt * 1024 + s0];
        bb[nt][1] = *(const bf16x8*)&bufB[boff + nt * 1024 + s1];
    }
}
template <int M0>
__device__ __forceinline__ void mfmaq(f32x4 (&acc)[8][4], bf16x8 (&aa)[2][2],
                                      bf16x8 (&bb)[4][2])
{
    __builtin_amdgcn_s_setprio(1);
#pragma unroll
    for (int m = 0; m < 2; m++)
#pragma unroll
        for (int nt = 0; nt < 4; nt++) {
            acc[M0 + m][nt] = __builtin_amdgcn_mfma_f32_16x16x32_bf16(
                aa[m][0], bb[nt][0], acc[M0 + m][nt], 0, 0, 0);
            acc[M0 + m][nt] = __builtin_amdgcn_mfma_f32_16x16x32_bf16(
                aa[m][1], bb[nt][1], acc[M0 + m][nt], 0, 0, 0);
        }
    __builtin_amdgcn_s_setprio(0);
}

__global__ __launch_bounds__(512, 2) void gemm8ph(
    const ushort* __restrict__ A, const ushort* __restrict__ B,
    ushort* __restrict__ g, int N, int K)
{
    alignas(16) __shared__ ushort lds[4][16384];   // A0,B0,A1,B1 (32 KiB each)
    ushort* const lA0 = lds[0];
    ushort* const lB0 = lds[1];
    ushort* const lA1 = lds[2];
    ushort* const lB1 = lds[3];

    const int tid = threadIdx.x;
    const int w = tid >> 6, lane = tid & 63;
    const int wr = w >> 2, wc = w & 3;
    const int fr = lane & 15, fq = lane >> 4;
    const int xk = fr & 7;

    const int nwg = gridDim.x;
    const int nbn = N >> 8;
    int id = (int)blockIdx.x;
    if (!(nwg & 7)) id = (id & 7) * (nwg >> 3) + (id >> 3);
    const int bm = id / nbn, bn = id - bm * nbn;

    const int srow = lane >> 3;
    const int scol = ((lane & 7) ^ srow) << 3;     // elements
    const ushort* Ag = A + (size_t)(bm * 256 + w * 8 + srow) * K + scol;
    const ushort* Bg = B + (size_t)(bn * 256 + w * 8 + srow) * K + scol;

    const int aoff = (wr * 128 + fr) * 64;
    const int boff = (wc * 64 + fr) * 64;
    const int s0 = ((0 + fq) ^ xk) << 3;           // kk=0 slot, elements
    const int s1 = ((4 + fq) ^ xk) << 3;           // kk=1 slot

    f32x4 acc[8][4];
#pragma unroll
    for (int i = 0; i < 8; i++)
#pragma unroll
        for (int j = 0; j < 4; j++) acc[i][j] = (f32x4){0.f, 0.f, 0.f, 0.f};

    bf16x8 aa[2][2], bb[4][2];

    STB(lB0, 0, 0);   STB(lB0, 64, 0);
    STA(lA0, 0, 0);   STA(lA0, 128, 0);
    STB(lB0, 128, 0); STB(lB0, 192, 0);
    STA(lA0, 64, 0);  STA(lA0, 192, 0);
    STB(lB1, 0, 1);   STB(lB1, 64, 1);
    STA(lA1, 0, 1);   STA(lA1, 128, 1);
    STB(lB1, 128, 1); STB(lB1, 192, 1);
    VMW(6);
    BARS;

    const int NITER = K >> 7;          // pairs of BK=64 tiles
    for (int i = 0; i < NITER - 1; i++) {
        const int t1 = 2 * i + 1, t2 = 2 * i + 2, t3 = 2 * i + 3;
        ldbq(bb, lB0, boff, s0, s1);
        ldaq(aa, lA0, 0, aoff, s0, s1);
        STA(lA1, 64, t1); STA(lA1, 192, t1);
        BARS; mfmaq<0>(acc, aa, bb); BARS;
        ldaq(aa, lA0, 2, aoff, s0, s1);
        STB(lB0, 0, t2); STB(lB0, 64, t2);
        BARS; mfmaq<2>(acc, aa, bb); BARS;
        ldaq(aa, lA0, 4, aoff, s0, s1);
        STA(lA0, 0, t2); STA(lA0, 128, t2);
        BARS; mfmaq<4>(acc, aa, bb); BARS;
        ldaq(aa, lA0, 6, aoff, s0, s1);
        STB(lB0, 128, t2); STB(lB0, 192, t2);
        BARS; mfmaq<6>(acc, aa, bb); VMW(6); BARS;
        ldbq(bb, lB1, boff, s0, s1);
        ldaq(aa, lA1, 0, aoff, s0, s1);
        STA(lA0, 64, t2); STA(lA0, 192, t2);
        BARS; mfmaq<0>(acc, aa, bb); BARS;
        ldaq(aa, lA1, 2, aoff, s0, s1);
        STB(lB1, 0, t3); STB(lB1, 64, t3);
        BARS; mfmaq<2>(acc, aa, bb); BARS;
        ldaq(aa, lA1, 4, aoff, s0, s1);
        STA(lA1, 0, t3); STA(lA1, 128, t3);
        BARS; mfmaq<4>(acc, aa, bb); BARS;
        ldaq(aa, lA1, 6, aoff, s0, s1);
        STB(lB1, 128, t3); STB(lB1, 192, t3);
        BARS; mfmaq<6>(acc, aa, bb); VMW(6); BARS;
    }
    {
        const int t1 = 2 * NITER - 1;
        ldbq(bb, lB0, boff, s0, s1);
        ldaq(aa, lA0, 0, aoff, s0, s1);
        STA(lA1, 64, t1); STA(lA1, 192, t1);
        BARS; mfmaq<0>(acc, aa, bb); BARS;
        ldaq(aa, lA0, 2, aoff, s0, s1);
        BARS; mfmaq<2>(acc, aa, bb); BARS;
        ldaq(aa, lA0, 4, aoff, s0, s1);
        BARS; mfmaq<4>(acc, aa, bb); BARS;
        ldaq(aa, lA0, 6, aoff, s0, s1);
        BARS; mfmaq<6>(acc, aa, bb); VMW(0); BARS;
        ldbq(bb, lB1, boff, s0, s1);
        ldaq(aa, lA1, 0, aoff, s0, s1);
        BARS; mfmaq<0>(acc, aa, bb); BARS;
        ldaq(aa, lA1, 2, aoff, s0, s1);
        BARS; mfmaq<2>(acc, aa, bb); BARS;
        ldaq(aa, lA1, 4, aoff, s0, s1);
        BARS; mfmaq<4>(acc, aa, bb); BARS;
        ldaq(aa, lA1, 6, aoff, s0, s1);
        mfmaq<6>(acc, aa, bb);
    }

    // ---- fused silu-mul epilogue: even nt = gate, odd nt = up, same col ----
    const int FFo = N >> 1;
#pragma unroll
    for (int mt = 0; mt < 8; mt++) {
#pragma unroll
        for (int u = 0; u < 2; u++) {
            const int col = (bn * 8 + wc * 2 + u) * 16 + fr;
#pragma unroll
            for (int r = 0; r < 4; r++) {
                const int row = bm * 256 + wr * 128 + mt * 16 + fq * 4 + r;
                const float xg = acc[mt][2 * u][r];
                const float xu = acc[mt][2 * u + 1][r];
                const float yv = xg / (1.f + __expf(-xg)) * xu;
                g[(size_t)row * FFo + col] = f2bf(yv);
            }
        }
    }
}

// ---------------------------------------------------------------------------
// Split-K MFMA GEMM: grid.z = SK slices of K. Raw fp32 partials to part.
// ---------------------------------------------------------------------------
__global__ __launch_bounds__(256) void mfma_gemm_sk(
    const ushort* __restrict__ A, const ushort* __restrict__ B,
    float* __restrict__ part, int M, int N, int K, int Kc)
{
    __shared__ ushort Alds[128 * 32];
    __shared__ ushort Blds[128 * 32];

    const int tid  = threadIdx.x;
    const int w    = tid >> 6;
    const int lane = tid & 63;
    const int bm = blockIdx.y, bn = blockIdx.x, z = blockIdx.z;
    const int wr = w >> 1, wc = w & 1;
    const int fr = lane & 15;
    const int fq = lane >> 4;
    const int srow = lane >> 2;
    const int skof = (lane & 3) * 8;

    f32x4 acc[4][4];
#pragma unroll
    for (int i = 0; i < 4; i++)
#pragma unroll
        for (int j = 0; j < 4; j++)
            acc[i][j] = (f32x4){0.f, 0.f, 0.f, 0.f};

    const int kbeg = z * Kc;
    for (int k0 = kbeg; k0 < kbeg + Kc; k0 += 32) {
        __syncthreads();
#pragma unroll
        for (int i = 0; i < 2; i++) {
            const int slot = w * 2 + i;
            const ushort* ga = &A[(size_t)(bm * 128 + slot * 16 + srow) * K + k0 + skof];
            __builtin_amdgcn_global_load_lds(
                (const __attribute__((address_space(1))) void*)ga,
                (__attribute__((address_space(3))) void*)&Alds[slot * 512], 16, 0, 0);
            const ushort* gb = &B[(size_t)(bn * 128 + slot * 16 + srow) * K + k0 + skof];
            __builtin_amdgcn_global_load_lds(
                (const __attribute__((address_space(1))) void*)gb,
                (__attribute__((address_space(3))) void*)&Blds[slot * 512], 16, 0, 0);
        }
        __syncthreads();

        bf16x8 a[4], b[4];
#pragma unroll
        for (int mt = 0; mt < 4; mt++)
            a[mt] = *(const bf16x8*)&Alds[(wr * 64 + mt * 16 + fr) * 32 + fq * 8];
#pragma unroll
        for (int nt = 0; nt < 4; nt++)
            b[nt] = *(const bf16x8*)&Blds[(wc * 64 + nt * 16 + fr) * 32 + fq * 8];

#pragma unroll
        for (int mt = 0; mt < 4; mt++)
#pragma unroll
            for (int nt = 0; nt < 4; nt++)
                acc[mt][nt] = __builtin_amdgcn_mfma_f32_16x16x32_bf16(
                    a[mt], b[nt], acc[mt][nt], 0, 0, 0);
    }

    float* pz = part + (size_t)z * M * N;
#pragma unroll
    for (int mt = 0; mt < 4; mt++)
#pragma unroll
        for (int nt = 0; nt < 4; nt++)
#pragma unroll
            for (int r = 0; r < 4; r++) {
                const int row = bm * 128 + wr * 64 + mt * 16 + fq * 4 + r;
                const int col = bn * 128 + wc * 64 + nt * 16 + fr;
                pz[(size_t)row * N + col] = acc[mt][nt][r];
            }
}

// ---------------------------------------------------------------------------
// Split-K reduce + epilogue (generic; q/kv/final-down use this).
// ---------------------------------------------------------------------------
__global__ __launch_bounds__(256) void sk_reduce(
    const float* __restrict__ part, int mn4, int n4,
    const float* __restrict__ bias, const float* __restrict__ addp,
    float oscale, float* __restrict__ outf, ushort* __restrict__ outb)
{
    const size_t mn = (size_t)mn4 * 4;
    int i = blockIdx.x * 256 + threadIdx.x;
    const int stride = gridDim.x * 256;
    for (; i < mn4; i += stride) {
        float4 v = ((const float4*)part)[i];
#pragma unroll
        for (int z = 1; z < SK_; z++) {
            const float4 pz = ((const float4*)(part + z * mn))[i];
            v.x += pz.x; v.y += pz.y; v.z += pz.z; v.w += pz.w;
        }
        v.x *= oscale; v.y *= oscale; v.z *= oscale; v.w *= oscale;
        if (bias) {
            const float bb = bias[i / n4];
            v.x += bb; v.y += bb; v.z += bb; v.w += bb;
        }
        if (addp) {
            const float4 ad = ((const float4*)addp)[i];
            v.x += ad.x; v.y += ad.y; v.z += ad.z; v.w += ad.w;
        }
        if (outf) ((float4*)outf)[i] = v;
        if (outb) {
            ushort4 r = {f2bf(v.x), f2bf(v.y), f2bf(v.z), f2bf(v.w)};
            ((ushort4*)outb)[i] = r;
        }
    }
}

// ---------------------------------------------------------------------------
// Fused split-K reduce + residual + RMSNorm. One block per row (N = H_).
//   resid = sum_z part_z[row] (+ bias[row]) (+ addp[row])
//   scale = rsqrt(mean(resid^2) + eps)
//   y / yb  = resid * scale * w      (fp32 + bf16 normed outputs)
//   residb  = bf16 of resid (optional; feeds the hidcomp residual rows)
// c4 = t + j*256 covers float4 slots {0..255} then {256..511}, coalesced.
// (R3 bug: t*2 + j*256 overflowed the row — fixed.)
// ---------------------------------------------------------------------------
__global__ __launch_bounds__(256) void sk_reduce_rms(
    const float* __restrict__ part, const float* __restrict__ bias,
    const float* __restrict__ addp, const float* __restrict__ w,
    ushort* __restrict__ residb, float* __restrict__ y,
    ushort* __restrict__ yb)
{
    constexpr size_t MN = (size_t)COMP_ * H_;
    const int row = blockIdx.x;
    const int t = threadIdx.x;
    __shared__ float red[256];

    float4 v[2];
#pragma unroll
    for (int j = 0; j < 2; j++) {
        const int c4 = t + j * 256;               // 512 float4 per row
        v[j] = ((const float4*)(part + (size_t)row * H_))[c4];
#pragma unroll
        for (int z = 1; z < SK_; z++) {
            const float4 pz = ((const float4*)(part + z * MN + (size_t)row * H_))[c4];
            v[j].x += pz.x; v[j].y += pz.y; v[j].z += pz.z; v[j].w += pz.w;
        }
        if (bias) {
            const float bb = bias[row];
            v[j].x += bb; v[j].y += bb; v[j].z += bb; v[j].w += bb;
        }
        if (addp) {
            const float4 ad = ((const float4*)(addp + (size_t)row * H_))[c4];
            v[j].x += ad.x; v[j].y += ad.y; v[j].z += ad.z; v[j].w += ad.w;
        }
        if (residb) {
            ushort4 r = {f2bf(v[j].x), f2bf(v[j].y), f2bf(v[j].z), f2bf(v[j].w)};
            ((ushort4*)(residb + (size_t)row * H_))[c4] = r;
        }
    }
    float s = 0.f;
#pragma unroll
    for (int j = 0; j < 2; j++)
        s += v[j].x * v[j].x + v[j].y * v[j].y + v[j].z * v[j].z + v[j].w * v[j].w;
    red[t] = s;
    __syncthreads();
    for (int k = 128; k > 0; k >>= 1) {
        if (t < k) red[t] += red[t + k];
        __syncthreads();
    }
    const float scale = rsqrtf(red[0] * (1.0f / H_) + EPS_);
#pragma unroll
    for (int j = 0; j < 2; j++) {
        const int c4 = t + j * 256;
        const float4 wv = ((const float4*)w)[c4];
        float4 nv;
        nv.x = v[j].x * scale * wv.x;
        nv.y = v[j].y * scale * wv.y;
        nv.z = v[j].z * scale * wv.z;
        nv.w = v[j].w * scale * wv.w;
        ((float4*)(y + (size_t)row * H_))[c4] = nv;
        ushort4 r = {f2bf(nv.x), f2bf(nv.y), f2bf(nv.z), f2bf(nv.w)};
        ((ushort4*)(yb + (size_t)row * H_))[c4] = r;
    }
}

// ---------------------------------------------------------------------------
// MFMA flash attention v2: KV-split, S^T formulation, lane-linear fragment
// LDS staged via global_load_lds (per-lane pre-permuted GLOBAL source, linear
// LDS dest — rule #21), double-buffered with async stage (T14), cvt_pk P-pack
// (T12), defer-max rescale THR=8 (T13), setprio around MFMA (T5).
// ---------------------------------------------------------------------------
__global__ __launch_bounds__(256) void attn_mfma(
    const ushort* __restrict__ q, const ushort* __restrict__ k, int ldk,
    const ushort* __restrict__ vt, float* __restrict__ attp,
    float* __restrict__ ml)
{
    constexpr int KSPAN = TOT_ / SP_;   // 1536 keys per split
    alignas(16) __shared__ ushort Kb[2][8 * 512];   // [buf][(h*4+nt)*512 + lane*8]
    alignas(16) __shared__ ushort Vb[2][8 * 512];
    alignas(16) __shared__ ushort Ps[64 * 64];      // XOR-swizzled

    const int qt = blockIdx.x, h = blockIdx.y, z = blockIdx.z;
    const int kvh = h / GROUPS_;
    const int tid = threadIdx.x;
    const int w = tid >> 6, lane = tid & 63;
    const int fr = lane & 15, fq = lane >> 4;
    const int q0 = qt * 64;

    const ushort* qrow = &q[(size_t)(q0 + w * 16 + fr) * H_ + h * HD_];
    const bf16x8 bq0 = *(const bf16x8*)(qrow + fq * 8);
    const bf16x8 bq1 = *(const bf16x8*)(qrow + 32 + fq * 8);

    float m = -1e30f, l = 0.f;          // per-lane row state (row = fr)
    f32x4 acc[4];
#pragma unroll
    for (int nt = 0; nt < 4; nt++) acc[nt] = (f32x4){0.f, 0.f, 0.f, 0.f};

    const int t_beg = z * KSPAN;
    const ushort* kp = &k[(size_t)(t_beg + w * 16 + fr) * ldk + kvh * HD_ + fq * 8];
    const ushort* vp = &vt[(size_t)(kvh * HD_ + w * 16 + fr) * TOT_ + t_beg + fq * 8];

#define ASTG(gp, lp) __builtin_amdgcn_global_load_lds( \
    (const __attribute__((address_space(1))) void*)(gp), \
    (__attribute__((address_space(3))) void*)(lp), 16, 0, 0)

    ASTG(kp,      &Kb[0][w * 512]);
    ASTG(kp + 32, &Kb[0][(4 + w) * 512]);
    ASTG(vp,      &Vb[0][w * 512]);
    ASTG(vp + 32, &Vb[0][(4 + w) * 512]);
    asm volatile("s_waitcnt vmcnt(0)" ::: "memory");
    __syncthreads();
    const ushort* kn = kp + (size_t)64 * ldk;   // next-tile sources
    const ushort* vn = vp + 64;

    const int pxor = (fr & 7) << 4;
    char* const psb = (char*)&Ps[(w * 16 + fr) * 64];

    const int NT = KSPAN / 64;          // 24
    int cur = 0;
    for (int t = 0; t < NT; t++) {
        f32x4 st[4];
        __builtin_amdgcn_s_setprio(1);
#pragma unroll
        for (int nt = 0; nt < 4; nt++) {
            const bf16x8 a0 = *(const bf16x8*)&Kb[cur][(nt * 64 + lane) * 8];
            const bf16x8 a1 = *(const bf16x8*)&Kb[cur][((4 + nt) * 64 + lane) * 8];
            f32x4 tacc = (f32x4){0.f, 0.f, 0.f, 0.f};
            tacc = __builtin_amdgcn_mfma_f32_16x16x32_bf16(a0, bq0, tacc, 0, 0, 0);
            tacc = __builtin_amdgcn_mfma_f32_16x16x32_bf16(a1, bq1, tacc, 0, 0, 0);
            st[nt] = tacc;
        }
        __builtin_amdgcn_s_setprio(0);

        if (t + 1 < NT) {
            ASTG(kn,      &Kb[cur ^ 1][w * 512]);
            ASTG(kn + 32, &Kb[cur ^ 1][(4 + w) * 512]);
            ASTG(vn,      &Vb[cur ^ 1][w * 512]);
            ASTG(vn + 32, &Vb[cur ^ 1][(4 + w) * 512]);
            kn += (size_t)64 * ldk;
            vn += 64;
        }

        float mt = st[0][0];
#pragma unroll
        for (int nt = 0; nt < 4; nt++)
#pragma unroll
            for (int r = 0; r < 4; r++) mt = fmaxf(mt, st[nt][r]);
        mt = fmaxf(mt, __shfl_xor(mt, 16));
        mt = fmaxf(mt, __shfl_xor(mt, 32));
        if (!__all(mt <= m + 8.0f)) {   // defer-max (T13)
            const float mnew = fmaxf(m, mt);
            const float alpha = exp2f(m - mnew);
            m = mnew;
            l *= alpha;
            const float ar0 = __shfl(alpha, fq * 4 + 0, 16);
            const float ar1 = __shfl(alpha, fq * 4 + 1, 16);
            const float ar2 = __shfl(alpha, fq * 4 + 2, 16);
            const float ar3 = __shfl(alpha, fq * 4 + 3, 16);
#pragma unroll
            for (int nt = 0; nt < 4; nt++) {
                acc[nt][0] *= ar0; acc[nt][1] *= ar1;
                acc[nt][2] *= ar2; acc[nt][3] *= ar3;
            }
        }
        float ss = 0.f;
#pragma unroll
        for (int nt = 0; nt < 4; nt++)
#pragma unroll
            for (int r = 0; r < 4; r++) {
                const float pv = exp2f(st[nt][r] - m);
                st[nt][r] = pv;
                ss += pv;
            }
        ss += __shfl_xor(ss, 16);
        ss += __shfl_xor(ss, 32);
        l += ss;

#pragma unroll
        for (int nt = 0; nt < 4; nt++) {
            uint2 uu;
            uu.x = cvtpk_bf16(st[nt][0], st[nt][1]);
            uu.y = cvtpk_bf16(st[nt][2], st[nt][3]);
            *(uint2*)(psb + ((nt * 32 + fq * 8) ^ pxor)) = uu;
        }
        const bf16x8 ap0 = *(const bf16x8*)(psb + ((fq * 16) ^ pxor));
        const bf16x8 ap1 = *(const bf16x8*)(psb + ((64 + fq * 16) ^ pxor));

        __builtin_amdgcn_s_setprio(1);
#pragma unroll
        for (int nt = 0; nt < 4; nt++) {
            const bf16x8 b0 = *(const bf16x8*)&Vb[cur][(nt * 64 + lane) * 8];
            const bf16x8 b1 = *(const bf16x8*)&Vb[cur][((4 + nt) * 64 + lane) * 8];
            acc[nt] = __builtin_amdgcn_mfma_f32_16x16x32_bf16(ap0, b0, acc[nt], 0, 0, 0);
            acc[nt] = __builtin_amdgcn_mfma_f32_16x16x32_bf16(ap1, b1, acc[nt], 0, 0, 0);
        }
        __builtin_amdgcn_s_setprio(0);

        asm volatile("s_waitcnt vmcnt(0)" ::: "memory");
        __syncthreads();
        cur ^= 1;
    }
#undef ASTG

    float* pz = attp + (size_t)z * COMP_ * H_;
#pragma unroll
    for (int r = 0; r < 4; r++) {
        const int row = q0 + w * 16 + fq * 4 + r;
#pragma unroll
        for (int nt = 0; nt < 4; nt++)
            pz[(size_t)row * H_ + h * HD_ + nt * 16 + fr] = acc[nt][r];
    }
    if (lane < 16)
        ((float2*)ml)[((size_t)z * NH_ + h) * COMP_ + (q0 + w * 16 + fr)] =
            make_float2(m, l);
}

// ---------------------------------------------------------------------------
// Merge the SP_ KV-splits.
// ---------------------------------------------------------------------------
__global__ __launch_bounds__(256) void attn_merge(
    const float* __restrict__ attp, const float* __restrict__ ml,
    ushort* __restrict__ o, int n4)
{
    constexpr int H4 = H_ / 4;
    constexpr size_t PS = (size_t)COMP_ * H_;
    int i = blockIdx.x * 256 + threadIdx.x;
    const int stride = gridDim.x * 256;
    for (; i < n4; i += stride) {
        const int row = i / H4;
        const int col = (i - row * H4) * 4;
        const int h = col >> 6;          // HD_ = 64
        const float2 ml0 = ((const float2*)ml)[((size_t)0 * NH_ + h) * COMP_ + row];
        const float2 ml1 = ((const float2*)ml)[((size_t)1 * NH_ + h) * COMP_ + row];
        const float M = fmaxf(ml0.x, ml1.x);
        const float a0 = exp2f(ml0.x - M), a1 = exp2f(ml1.x - M);
        const float inv = 1.0f / (a0 * ml0.y + a1 * ml1.y);
        const float4 p0 = ((const float4*)attp)[i];
        const float4 p1 = ((const float4*)(attp + PS))[i];
        ushort4 r = {f2bf((a0 * p0.x + a1 * p1.x) * inv),
                     f2bf((a0 * p0.y + a1 * p1.y) * inv),
                     f2bf((a0 * p0.z + a1 * p1.z) * inv),
                     f2bf((a0 * p0.w + a1 * p1.w) * inv)};
        ((ushort4*)o)[i] = r;
    }
}

// ---------------------------------------------------------------------------
extern "C" void kernel_launch(void* const* d_in, const int* in_sizes, int n_in,
                              void* d_out, int out_size, void* d_ws, size_t ws_size,
                              hipStream_t stream)
{
    (void)in_sizes; (void)n_in; (void)out_size; (void)ws_size;

    const float* hidden      = (const float*)d_in[0];
    const float* comp_w      = (const float*)d_in[1];
    const float* comp_b      = (const float*)d_in[2];
    const float* q_w         = (const float*)d_in[3];
    const float* k_w         = (const float*)d_in[4];
    const float* v_w         = (const float*)d_in[5];
    const float* o_w         = (const float*)d_in[6];
    const float* attn_norm_w = (const float*)d_in[7];
    const float* mlp_norm_w  = (const float*)d_in[8];
    const float* gate_w      = (const float*)d_in[9];
    const float* up_w        = (const float*)d_in[10];
    const float* down_w      = (const float*)d_in[11];
    float* out = (float*)d_out;

    char* p = (char*)d_ws;
    auto alloc = [&](size_t bytes) -> char* {
        char* r = p; p += (bytes + 255) & ~(size_t)255; return r;
    };
    // bf16 weights (kv fused = stacked rows; gate/up 16-col interleaved)
    ushort* qw_bf    = (ushort*)alloc((size_t)H_ * H_ * 2);
    ushort* kvw_bf   = (ushort*)alloc((size_t)KV2_ * H_ * 2);
    ushort* ow_bf    = (ushort*)alloc((size_t)H_ * H_ * 2);
    ushort* guw_bf   = (ushort*)alloc((size_t)GU2_ * H_ * 2);
    ushort* down_bf  = (ushort*)alloc((size_t)H_ * FF_ * 2);
    ushort* compw_bf = (ushort*)alloc((size_t)COMP_ * S_ * 2);
    // bf16 activation buffers
    ushort* hidcomp  = (ushort*)alloc((size_t)TOT_ * H_ * 2);   // [hidden; compressed]
    ushort* hidT     = (ushort*)alloc((size_t)H_ * S_ * 2);
    ushort* ct_bf    = (ushort*)alloc((size_t)COMP_ * H_ * 2);
    ushort* ct2_bf   = (ushort*)alloc((size_t)COMP_ * H_ * 2);
    ushort* ob_bf    = (ushort*)alloc((size_t)COMP_ * H_ * 2);
    ushort* qb_bf    = (ushort*)alloc((size_t)COMP_ * H_ * 2);
    ushort* kvb_bf   = (ushort*)alloc((size_t)TOT_ * KV2_ * 2); // k cols 0..511, v cols 512..1023
    ushort* vt_bf    = (ushort*)alloc((size_t)KV_ * TOT_ * 2);
    ushort* gb_bf    = (ushort*)alloc((size_t)COMP_ * FF_ * 2);
    // fp32 normed activations (residual adds)
    float* ct    = (float*)alloc((size_t)COMP_ * H_ * 4);
    float* ct2   = (float*)alloc((size_t)COMP_ * H_ * 4);
    // split-K scratch; time-shared with attention partials
    float*  skbuf = (float*)alloc((size_t)SK_ * TOT_ * KV2_ * 4);
    float*  attp  = skbuf;                                // SP_ x (COMP_, H_) fp32
    float*  mlbuf = skbuf + (size_t)SP_ * COMP_ * H_;     // SP_*NH_*COMP_ float2

    ushort* cur_bf = hidcomp + (size_t)S_ * H_;   // compressed rows of hidcomp

    const dim3 blk(256);

    // ---- one-time converts ----
    f2b_k<<<512, blk, 0, stream>>>(q_w,    qw_bf,            H_ * H_ / 4);
    f2b_k<<<512, blk, 0, stream>>>(k_w,    kvw_bf,           KV_ * H_ / 4);
    f2b_k<<<512, blk, 0, stream>>>(v_w,    kvw_bf + (size_t)KV_ * H_, KV_ * H_ / 4);
    f2b_k<<<512, blk, 0, stream>>>(o_w,    ow_bf,            H_ * H_ / 4);
    f2b_gu<<<1024, blk, 0, stream>>>(gate_w, up_w, guw_bf,   GU2_ * H_ / 4);
    f2b_k<<<512, blk, 0, stream>>>(down_w, down_bf,          H_ * FF_ / 4);
    f2b_k<<<512, blk, 0, stream>>>(comp_w, compw_bf,         COMP_ * S_ / 4);
    f2b_k<<<512, blk, 0, stream>>>(hidden, hidcomp,          S_ * H_ / 4);
    tpose64<<<dim3(S_ / 64, H_ / 64), blk, 0, stream>>>(hidcomp, hidT, S_, H_, H_);

    // compressed = comp_w @ hidden + comp_b; fused resid-bf16 + attn RMSNorm
    mfma_gemm_sk<<<dim3(H_ / 128, COMP_ / 128, SK_), blk, 0, stream>>>(
        compw_bf, hidT, skbuf, COMP_, H_, S_, S_ / SK_);
    sk_reduce_rms<<<COMP_, blk, 0, stream>>>(
        skbuf, comp_b, nullptr, attn_norm_w, cur_bf, ct, ct_bf);

    for (int d = 0; d < 2; d++) {
        // q = (log2e/8) * (ct @ q_w^T)   [split-K; exp2-domain scaling]
        mfma_gemm_sk<<<dim3(H_ / 128, COMP_ / 128, SK_), blk, 0, stream>>>(
            ct_bf, qw_bf, skbuf, COMP_, H_, H_, H_ / SK_);
        sk_reduce<<<1024, blk, 0, stream>>>(
            skbuf, COMP_ * H_ / 4, H_ / 4, nullptr, nullptr, 0.125f * LOG2E_,
            nullptr, qb_bf);

        // k|v = [hidden; compressed] @ [k_w; v_w]^T   [split-K, fused]
        mfma_gemm_sk<<<dim3(KV2_ / 128, TOT_ / 128, SK_), blk, 0, stream>>>(
            hidcomp, kvw_bf, skbuf, TOT_, KV2_, H_, H_ / SK_);
        sk_reduce<<<1024, blk, 0, stream>>>(
            skbuf, TOT_ * KV2_ / 4, KV2_ / 4, nullptr, nullptr, 1.f, nullptr, kvb_bf);

        // vt = transpose of v half (row-stride KV2_)
        tpose64<<<dim3(TOT_ / 64, KV_ / 64), blk, 0, stream>>>(
            kvb_bf + KV_, vt_bf, TOT_, KV_, KV2_);

        // attention (MFMA flash v2) + merge
        attn_mfma<<<dim3(COMP_ / 64, NH_, SP_), blk, 0, stream>>>(
            qb_bf, kvb_bf, KV2_, vt_bf, attp, mlbuf);
        attn_merge<<<512, blk, 0, stream>>>(attp, mlbuf, ob_bf, COMP_ * H_ / 4);

        // compressed = o @ o_w^T + ct; fused mlp RMSNorm -> ct2/ct2_bf
        mfma_gemm_sk<<<dim3(H_ / 128, COMP_ / 128, SK_), blk, 0, stream>>>(
            ob_bf, ow_bf, skbuf, COMP_, H_, H_, H_ / SK_);
        sk_reduce_rms<<<COMP_, blk, 0, stream>>>(
            skbuf, nullptr, ct, mlp_norm_w, nullptr, ct2, ct2_bf);

        // gate|up fused GEMM with in-epilogue silu-mul -> gb_bf (COMP_, FF_)
        gemm8ph<<<dim3((GU2_ / 256) * (COMP_ / 256)), dim3(512), 0, stream>>>(
            ct2_bf, guw_bf, gb_bf, GU2_, H_);

        // compressed = g @ down_w^T + ct2   [split-K, Kc = 1408]
        mfma_gemm_sk<<<dim3(H_ / 128, COMP_ / 128, SK_), blk, 0, stream>>>(
            gb_bf, down_bf, skbuf, COMP_, H_, FF_, FF_ / SK_);
        if (d == 0) {
            // fused resid-bf16 + next-iter attn RMSNorm
            sk_reduce_rms<<<COMP_, blk, 0, stream>>>(
                skbuf, nullptr, ct2, attn_norm_w, cur_bf, ct, ct_bf);
        } else {
            sk_reduce<<<1024, blk, 0, stream>>>(
                skbuf, COMP_ * H_ / 4, H_ / 4, nullptr, ct2, 1.f, out, nullptr);
        }
    }
}